// Round 10
// baseline (1493.362 us; speedup 1.0000x reference)
//
#include <hip/hip_runtime.h>

#define NN 20000
#define NE 320000
#define NG 64
#define D 128
#define D3 384
#define NRBF 20
#define RBF_ROW 24       // fp32 per rbf row -> 96B, 16B-aligned
#define PI_F 3.14159265358979323846f
#define RCUT 10.0f

typedef unsigned int uint;
typedef unsigned short ushort;
typedef __attribute__((ext_vector_type(8))) short bf16x8;
typedef __attribute__((ext_vector_type(4))) float f32x4;

__device__ __forceinline__ float silu_f(float x) {
    return x / (1.0f + __expf(-x));
}
__device__ __forceinline__ float b2f(ushort u) {
    return __uint_as_float(((uint)u) << 16);
}
__device__ __forceinline__ ushort f2b(float f) {
    uint u = __float_as_uint(f);
    u = u + 0x7fffu + ((u >> 16) & 1u);
    return (ushort)(u >> 16);
}
__device__ __forceinline__ float plo(uint u) { return __uint_as_float(u << 16); }
__device__ __forceinline__ float phi_(uint u) { return __uint_as_float(u & 0xffff0000u); }

#define MFMA3(acc, aH, aL, bH, bL)                                          \
    acc = __builtin_amdgcn_mfma_f32_16x16x32_bf16(aL, bH, acc, 0, 0, 0);    \
    acc = __builtin_amdgcn_mfma_f32_16x16x32_bf16(aH, bL, acc, 0, 0, 0);    \
    acc = __builtin_amdgcn_mfma_f32_16x16x32_bf16(aH, bH, acc, 0, 0, 0);

// ---------------------------------------------------------------- init
__global__ __launch_bounds__(256) void init_all(
    const int* __restrict__ atype, const float* __restrict__ emb,
    float* __restrict__ s, float* __restrict__ v, float* __restrict__ g,
    int* __restrict__ deg, uint* __restrict__ pv_u, int* __restrict__ bcount)
{
    int idx = blockIdx.x * blockDim.x + threadIdx.x;
    int stride = gridDim.x * blockDim.x;
    if (idx < NN * D) {
        int n = idx >> 7, d = idx & 127;
        s[idx] = emb[atype[n] * D + d];
    }
    if (idx < NG * D) g[idx] = 0.0f;
    if (idx < NN) deg[idx] = 0;
    if (idx < 64) bcount[idx] = 0;
    for (int i = idx; i < NN * 3 * D; i += stride) v[i] = 0.0f;
    for (int i = idx; i < NN * 384; i += stride) pv_u[i] = 0u;   // pv rows (phi+v bf16)
}

// ---------------------------------------------------------------- weight pack: phi MLP
__global__ __launch_bounds__(256) void pack_phi_w(
    const float* __restrict__ w1, const float* __restrict__ w2,
    ushort* __restrict__ w1th, ushort* __restrict__ w1tl,
    ushort* __restrict__ w2th, ushort* __restrict__ w2tl)
{
    int idx = blockIdx.x * blockDim.x + threadIdx.x;
    if (idx < D * D) {
        int j = idx >> 7, k = idx & 127;
        float x = w1[k * D + j];
        ushort h = f2b(x);
        w1th[idx] = h;
        w1tl[idx] = f2b(x - b2f(h));
    }
    if (idx < D3 * D) {
        int j = idx >> 7, k = idx & 127;
        float x = w2[k * D3 + j];
        ushort h = f2b(x);
        w2th[idx] = h;
        w2tl[idx] = f2b(x - b2f(h));
    }
}

// ---------------------------------------------------------------- weight pack: update block
__global__ __launch_bounds__(256) void pack_upd_w(
    const float* __restrict__ Uw, const float* __restrict__ Vw,
    const float* __restrict__ w1, const float* __restrict__ w2,
    ushort* __restrict__ uwt, ushort* __restrict__ vwt,
    ushort* __restrict__ u1t, ushort* __restrict__ u2t)
{
    int idx = blockIdx.x * blockDim.x + threadIdx.x;
    if (idx < D * D) {
        int j = idx >> 7, k = idx & 127;
        float x = Uw[k * D + j];
        ushort h = f2b(x);
        uwt[idx] = h; uwt[D * D + idx] = f2b(x - b2f(h));
        float y = Vw[k * D + j];
        ushort g = f2b(y);
        vwt[idx] = g; vwt[D * D + idx] = f2b(y - b2f(g));
    }
    if (idx < 2 * D * D) {
        int j = idx >> 8, k = idx & 255;
        float x = w1[k * D + j];
        ushort h = f2b(x);
        u1t[idx] = h; u1t[2 * D * D + idx] = f2b(x - b2f(h));
    }
    if (idx < D3 * D) {
        int j = idx >> 7, k = idx & 127;
        float x = w2[k * D3 + j];
        ushort h = f2b(x);
        u2t[idx] = h; u2t[D3 * D + idx] = f2b(x - b2f(h));
    }
}

// ---------------------------------------------------------------- CSR build (by dst)
__global__ __launch_bounds__(256) void csr_count(
    const int* __restrict__ dst, int* __restrict__ deg)
{
    int e = blockIdx.x * blockDim.x + threadIdx.x;
    if (e < NE) atomicAdd(&deg[dst[e]], 1);
}

__global__ __launch_bounds__(1024) void csr_scan(
    const int* __restrict__ deg, int* __restrict__ offs, int* __restrict__ cursor)
{
    __shared__ int part[1024];
    int t = threadIdx.x;
    const int per = (NN + 1023) / 1024;  // 20
    int base = t * per;
    int sum = 0;
    for (int i = 0; i < per; i++) {
        int idx = base + i;
        if (idx < NN) sum += deg[idx];
    }
    part[t] = sum;
    __syncthreads();
    for (int off = 1; off < 1024; off <<= 1) {
        int vv = (t >= off) ? part[t - off] : 0;
        __syncthreads();
        part[t] += vv;
        __syncthreads();
    }
    int run = part[t] - sum;
    for (int i = 0; i < per; i++) {
        int idx = base + i;
        if (idx < NN) {
            offs[idx] = run;
            cursor[idx] = run;
            run += deg[idx];
        }
    }
    if (t == 1023) offs[NN] = run;
}

__global__ __launch_bounds__(256) void csr_scatter(
    const int* __restrict__ dst, int* __restrict__ cursor, int* __restrict__ eid)
{
    int e = blockIdx.x * blockDim.x + threadIdx.x;
    if (e < NE) {
        int p = atomicAdd(&cursor[dst[e]], 1);
        eid[p] = e;
    }
}

// ---------------------------------------------------------------- degree sort (counting)
__global__ __launch_bounds__(256) void dbucket(
    const int* __restrict__ deg, int* __restrict__ bcount)
{
    int n = blockIdx.x * blockDim.x + threadIdx.x;
    if (n < NN) {
        int b = deg[n]; if (b > 63) b = 63;
        atomicAdd(&bcount[b], 1);
    }
}

__global__ void dscan(const int* __restrict__ bcount, int* __restrict__ bpos)
{
    if (threadIdx.x == 0) {
        int run = 0;
        for (int b = 63; b >= 0; b--) { bpos[b] = run; run += bcount[b]; }
    }
}

__global__ __launch_bounds__(256) void dscatter(
    const int* __restrict__ deg, int* __restrict__ bpos, int* __restrict__ perm)
{
    int n = blockIdx.x * blockDim.x + threadIdx.x;
    if (n < NN) {
        int b = deg[n]; if (b > 63) b = 63;
        int p = atomicAdd(&bpos[b], 1);
        perm[p] = n;
    }
}

// ---------------------------------------------------------------- edge geometry
__global__ __launch_bounds__(256) void edge_geom(
    const float* __restrict__ evec,
    float* __restrict__ rbf, float4* __restrict__ geo)
{
    int e = blockIdx.x * blockDim.x + threadIdx.x;
    if (e >= NE) return;
    float x = evec[e * 3 + 0], y = evec[e * 3 + 1], z = evec[e * 3 + 2];
    float r = sqrtf(x * x + y * y + z * z);
    float inv = 1.0f / r;
    float f = (r < RCUT) ? 0.5f * (cosf(PI_F * r / RCUT) + 1.0f) : 0.0f;
    float4 g;
    g.x = x * inv; g.y = y * inv; g.z = z * inv; g.w = f;
    geo[e] = g;
    float base = PI_F * r / RCUT;
    float sf = inv * f;
    #pragma unroll
    for (int k = 0; k < NRBF; k++) {
        rbf[(size_t)e * RBF_ROW + k] = sinf((float)(k + 1) * base) * sf;
    }
}

// ---------------------------------------------------------------- phi MLP via MFMA bf16x3
// writes phi into pv rows: pv[n][ch][slot 0..2]
__global__ __launch_bounds__(256) void phi_mlp_mfma(
    const float* __restrict__ s,
    const ushort* __restrict__ w1th, const ushort* __restrict__ w1tl,
    const float* __restrict__ b1,
    const ushort* __restrict__ w2th, const ushort* __restrict__ w2tl,
    const float* __restrict__ b2,
    ushort* __restrict__ pv)
{
    __shared__ ushort ah[4][16][136];
    __shared__ ushort al[4][16][136];
    int wave = threadIdx.x >> 6, lane = threadIdx.x & 63;
    int r0 = (blockIdx.x * 4 + wave) * 16;
    bool act = (r0 < NN);

    if (act) {
        #pragma unroll
        for (int t = 0; t < 8; t++) {
            int flat = t * 256 + lane * 4;
            int row = flat >> 7, col = flat & 127;
            float4 sv = *(const float4*)&s[(size_t)(r0 + row) * D + col];
            ushort h0 = f2b(sv.x), h1 = f2b(sv.y), h2 = f2b(sv.z), h3 = f2b(sv.w);
            ushort l0 = f2b(sv.x - b2f(h0)), l1 = f2b(sv.y - b2f(h1));
            ushort l2 = f2b(sv.z - b2f(h2)), l3 = f2b(sv.w - b2f(h3));
            uint2 ph; ph.x = (uint)h0 | ((uint)h1 << 16); ph.y = (uint)h2 | ((uint)h3 << 16);
            uint2 pl; pl.x = (uint)l0 | ((uint)l1 << 16); pl.y = (uint)l2 | ((uint)l3 << 16);
            *(uint2*)&ah[wave][row][col] = ph;
            *(uint2*)&al[wave][row][col] = pl;
        }
    }
    __syncthreads();

    int arow = lane & 15, kg = lane >> 4;
    bf16x8 aH[4], aL[4];
    if (act) {
        #pragma unroll
        for (int t = 0; t < 4; t++) {
            aH[t] = *(const bf16x8*)&ah[wave][arow][t * 32 + kg * 8];
            aL[t] = *(const bf16x8*)&al[wave][arow][t * 32 + kg * 8];
        }
    }
    __syncthreads();

    if (act) {
        #pragma unroll
        for (int jb = 0; jb < 8; jb++) {
            f32x4 acc = {0.f, 0.f, 0.f, 0.f};
            #pragma unroll
            for (int t = 0; t < 4; t++) {
                bf16x8 bh = *(const bf16x8*)&w1th[(size_t)(jb * 16 + arow) * 128 + t * 32 + kg * 8];
                bf16x8 bl = *(const bf16x8*)&w1tl[(size_t)(jb * 16 + arow) * 128 + t * 32 + kg * 8];
                acc = __builtin_amdgcn_mfma_f32_16x16x32_bf16(aH[t], bh, acc, 0, 0, 0);
                acc = __builtin_amdgcn_mfma_f32_16x16x32_bf16(aH[t], bl, acc, 0, 0, 0);
                acc = __builtin_amdgcn_mfma_f32_16x16x32_bf16(aL[t], bh, acc, 0, 0, 0);
            }
            float bias = b1[jb * 16 + arow];
            #pragma unroll
            for (int r = 0; r < 4; r++) {
                float hv = silu_f(acc[r] + bias);
                ushort hh = f2b(hv);
                ah[wave][kg * 4 + r][jb * 16 + arow] = hh;
                al[wave][kg * 4 + r][jb * 16 + arow] = f2b(hv - b2f(hh));
            }
        }
    }
    __syncthreads();

    if (act) {
        bf16x8 hH[4], hL[4];
        #pragma unroll
        for (int t = 0; t < 4; t++) {
            hH[t] = *(const bf16x8*)&ah[wave][arow][t * 32 + kg * 8];
            hL[t] = *(const bf16x8*)&al[wave][arow][t * 32 + kg * 8];
        }
        #pragma unroll
        for (int jb = 0; jb < 24; jb++) {
            f32x4 acc = {0.f, 0.f, 0.f, 0.f};
            #pragma unroll
            for (int t = 0; t < 4; t++) {
                bf16x8 bh = *(const bf16x8*)&w2th[(size_t)(jb * 16 + arow) * 128 + t * 32 + kg * 8];
                bf16x8 bl = *(const bf16x8*)&w2tl[(size_t)(jb * 16 + arow) * 128 + t * 32 + kg * 8];
                acc = __builtin_amdgcn_mfma_f32_16x16x32_bf16(hH[t], bh, acc, 0, 0, 0);
                acc = __builtin_amdgcn_mfma_f32_16x16x32_bf16(hH[t], bl, acc, 0, 0, 0);
                acc = __builtin_amdgcn_mfma_f32_16x16x32_bf16(hL[t], bh, acc, 0, 0, 0);
            }
            float bias = b2[jb * 16 + arow];
            int seg = jb >> 3;                  // phi segment 0..2 -> pv slot
            int ch  = (jb & 7) * 16 + arow;     // channel 0..127
            #pragma unroll
            for (int r = 0; r < 4; r++) {
                pv[((size_t)(r0 + kg * 4 + r) * 128 + ch) * 6 + seg] = f2b(acc[r] + bias);
            }
        }
    }
}

// ---------------------------------------------------------------- node gather
// 512 threads = 8 waves = 4 nodes x 2 channel-halves; nodes via degree-sorted perm.
// Per edge per lane: ONE dwordx3 load of pv[src][d] = {phi0,phi1,phi2,v0,v1,v2} bf16.
// Filter weights in 60 VGPRs; rbf/geo wave-uniform -> scalar loads.
// waves_per_eu(8,8): VGPR fits 64 (compiler used 56 unforced) -> 8 waves/SIMD to
// cover the ~33% latency gap seen at (4,4) (VALUBusy 67%).
__global__ __launch_bounds__(512)
__attribute__((amdgpu_waves_per_eu(8, 8)))
void node_gather(
    const int* __restrict__ eid, const int* __restrict__ offs,
    const int* __restrict__ perm, const int* __restrict__ src,
    const ushort* __restrict__ pv,
    const float* __restrict__ s_old, const float* __restrict__ v_old,
    const float* __restrict__ rbf, const float4* __restrict__ geo,
    const float* __restrict__ filt_w, const float* __restrict__ filt_b,
    float* __restrict__ s_new, float* __restrict__ v_new)
{
    int wave = threadIdx.x >> 6;
    int lane = threadIdx.x & 63;
    int widx = blockIdx.x * 4 + (wave >> 1);
    if (widx >= NN) return;
    int node = __builtin_amdgcn_readfirstlane(perm[widx]);
    int half = wave & 1;
    int d = half * 64 + lane;

    float wr0[NRBF], wr1[NRBF], wr2[NRBF];
    #pragma unroll
    for (int k = 0; k < NRBF; k++) {
        wr0[k] = filt_w[k * D3 + d];
        wr1[k] = filt_w[k * D3 + D + d];
        wr2[k] = filt_w[k * D3 + 2 * D + d];
    }
    float fb0 = filt_b[d], fb1 = filt_b[D + d], fb2 = filt_b[2 * D + d];
    int e0 = __builtin_amdgcn_readfirstlane(offs[node]);
    int e1 = __builtin_amdgcn_readfirstlane(offs[node + 1]);

    float acc_s = 0.f, av0 = 0.f, av1 = 0.f, av2 = 0.f;
    size_t doff = (size_t)d * 6;   // lane's ushort offset inside a pv row

    for (int i = e0; i < e1; i++) {
        int e  = __builtin_amdgcn_readfirstlane(eid[i]);
        int sn = __builtin_amdgcn_readfirstlane(src[e]);
        float4 g = geo[e];                              // scalar load (uniform)
        const float* rp = rbf + (size_t)e * RBF_ROW;    // scalar loads (uniform)
        uint3 pk = *(const uint3*)(pv + (size_t)sn * 768 + doff);
        float p0 = plo(pk.x), p1 = phi_(pk.x), p2 = plo(pk.y);
        float v0 = phi_(pk.y), v1 = plo(pk.z), v2 = phi_(pk.z);

        float W0 = g.w * fb0, W1 = g.w * fb1, W2 = g.w * fb2;
        #pragma unroll
        for (int k = 0; k < NRBF; k++) {
            float rk = rp[k];
            W0 += rk * wr0[k];
            W1 += rk * wr1[k];
            W2 += rk * wr2[k];
        }
        float m1 = p0 * W0, m2 = p1 * W1, m3 = p2 * W2;
        acc_s += m2;
        av0 += v0 * m1 + g.x * m3;
        av1 += v1 * m1 + g.y * m3;
        av2 += v2 * m1 + g.z * m3;
    }

    s_new[node * D + d] = s_old[node * D + d] + acc_s;
    v_new[(node * 3 + 0) * D + d] = v_old[(node * 3 + 0) * D + d] + av0;
    v_new[(node * 3 + 1) * D + d] = v_old[(node * 3 + 1) * D + d] + av1;
    v_new[(node * 3 + 2) * D + d] = v_old[(node * 3 + 2) * D + d] + av2;
}

// ---------------------------------------------------------------- fused update via MFMA bf16x3
// (R7, verified) — epilogue writes v bf16 into pv slots 3..5
__global__ __launch_bounds__(256) void node_vupd_mfma(
    float* __restrict__ s, float* __restrict__ v, ushort* __restrict__ pv,
    const ushort* __restrict__ uwt, const ushort* __restrict__ vwt,
    const ushort* __restrict__ u1t, const ushort* __restrict__ u2t,
    const float* __restrict__ b1, const float* __restrict__ b2)
{
    __shared__ __align__(16) char smem[59904];
    float*  U_lds  = (float*)(smem);             // [48][132]
    float*  UV_lds = (float*)(smem + 25344);     // [16][132]
    ushort* a_hi   = (ushort*)(smem + 33792);    // [48][136]
    ushort* a_lo   = a_hi + 48 * 136;
    ushort* x_hi   = (ushort*)(smem + 33792);    // [16][264]
    ushort* x_lo   = x_hi + 16 * 264;
    ushort* h_hi   = x_lo + 16 * 264;            // [16][136]
    ushort* h_lo   = h_hi + 16 * 136;
    float*  a_out  = (float*)(smem + 33792);     // [16][392]

    int tid = threadIdx.x;
    int wave = tid >> 6, lane = tid & 63;
    int arow = lane & 15, kg = lane >> 4;
    int n0 = blockIdx.x * 16;

    #pragma unroll
    for (int it = 0; it < 6; it++) {
        int f4 = it * 256 + tid;
        int row = f4 >> 5;
        int c4 = (f4 & 31) * 4;
        int i = row >> 4, n = row & 15;
        float4 vv = *(const float4*)&v[((size_t)(n0 + n) * 3 + i) * D + c4];
        ushort h0 = f2b(vv.x), h1 = f2b(vv.y), h2 = f2b(vv.z), h3 = f2b(vv.w);
        ushort l0 = f2b(vv.x - b2f(h0)), l1 = f2b(vv.y - b2f(h1));
        ushort l2 = f2b(vv.z - b2f(h2)), l3 = f2b(vv.w - b2f(h3));
        uint2 ph; ph.x = (uint)h0 | ((uint)h1 << 16); ph.y = (uint)h2 | ((uint)h3 << 16);
        uint2 pl; pl.x = (uint)l0 | ((uint)l1 << 16); pl.y = (uint)l2 | ((uint)l3 << 16);
        *(uint2*)&a_hi[row * 136 + c4] = ph;
        *(uint2*)&a_lo[row * 136 + c4] = pl;
    }
    __syncthreads();

    f32x4 accU[3][2], accVp[3][2];
    #pragma unroll
    for (int i = 0; i < 3; i++)
        #pragma unroll
        for (int jtl = 0; jtl < 2; jtl++) {
            accU[i][jtl] = (f32x4){0.f, 0.f, 0.f, 0.f};
            accVp[i][jtl] = (f32x4){0.f, 0.f, 0.f, 0.f};
        }
    #pragma unroll
    for (int i = 0; i < 3; i++) {
        #pragma unroll
        for (int t = 0; t < 4; t++) {
            bf16x8 aH = *(const bf16x8*)&a_hi[(i * 16 + arow) * 136 + t * 32 + kg * 8];
            bf16x8 aL = *(const bf16x8*)&a_lo[(i * 16 + arow) * 136 + t * 32 + kg * 8];
            #pragma unroll
            for (int jtl = 0; jtl < 2; jtl++) {
                int j = (wave * 2 + jtl) * 16 + arow;
                bf16x8 bH = *(const bf16x8*)&uwt[(size_t)j * 128 + t * 32 + kg * 8];
                bf16x8 bL = *(const bf16x8*)&uwt[(size_t)D * D + (size_t)j * 128 + t * 32 + kg * 8];
                MFMA3(accU[i][jtl], aH, aL, bH, bL)
                bf16x8 cH = *(const bf16x8*)&vwt[(size_t)j * 128 + t * 32 + kg * 8];
                bf16x8 cL = *(const bf16x8*)&vwt[(size_t)D * D + (size_t)j * 128 + t * 32 + kg * 8];
                MFMA3(accVp[i][jtl], aH, aL, cH, cL)
            }
        }
    }
    __syncthreads();

    #pragma unroll
    for (int jtl = 0; jtl < 2; jtl++) {
        int jcol = (wave * 2 + jtl) * 16 + arow;
        #pragma unroll
        for (int r = 0; r < 4; r++) {
            int n = kg * 4 + r;
            #pragma unroll
            for (int i = 0; i < 3; i++)
                U_lds[(i * 16 + n) * 132 + jcol] = accU[i][jtl][r];
            float uv = accU[0][jtl][r] * accVp[0][jtl][r]
                     + accU[1][jtl][r] * accVp[1][jtl][r]
                     + accU[2][jtl][r] * accVp[2][jtl][r];
            float nn = accVp[0][jtl][r] * accVp[0][jtl][r]
                     + accVp[1][jtl][r] * accVp[1][jtl][r]
                     + accVp[2][jtl][r] * accVp[2][jtl][r];
            UV_lds[n * 132 + jcol] = uv;
            float vn = sqrtf(nn);
            ushort hh = f2b(vn);
            x_hi[n * 264 + jcol] = hh;
            x_lo[n * 264 + jcol] = f2b(vn - b2f(hh));
        }
    }
    for (int t8 = tid; t8 < 16 * 128; t8 += 256) {
        int n = t8 >> 7, j = t8 & 127;
        float sv = s[(size_t)(n0 + n) * D + j];
        ushort hh = f2b(sv);
        x_hi[n * 264 + 128 + j] = hh;
        x_lo[n * 264 + 128 + j] = f2b(sv - b2f(hh));
    }
    __syncthreads();

    {
        f32x4 acc1[2];
        acc1[0] = (f32x4){0.f, 0.f, 0.f, 0.f};
        acc1[1] = (f32x4){0.f, 0.f, 0.f, 0.f};
        #pragma unroll
        for (int t = 0; t < 8; t++) {
            bf16x8 aH = *(const bf16x8*)&x_hi[arow * 264 + t * 32 + kg * 8];
            bf16x8 aL = *(const bf16x8*)&x_lo[arow * 264 + t * 32 + kg * 8];
            #pragma unroll
            for (int jtl = 0; jtl < 2; jtl++) {
                int j = (wave * 2 + jtl) * 16 + arow;
                bf16x8 bH = *(const bf16x8*)&u1t[(size_t)j * 256 + t * 32 + kg * 8];
                bf16x8 bL = *(const bf16x8*)&u1t[(size_t)2 * D * D + (size_t)j * 256 + t * 32 + kg * 8];
                MFMA3(acc1[jtl], aH, aL, bH, bL)
            }
        }
        #pragma unroll
        for (int jtl = 0; jtl < 2; jtl++) {
            int j = (wave * 2 + jtl) * 16 + arow;
            float bias = b1[j];
            #pragma unroll
            for (int r = 0; r < 4; r++) {
                int n = kg * 4 + r;
                float hv = silu_f(acc1[jtl][r] + bias);
                ushort hh = f2b(hv);
                h_hi[n * 136 + j] = hh;
                h_lo[n * 136 + j] = f2b(hv - b2f(hh));
            }
        }
    }
    __syncthreads();

    f32x4 acc2[6];
    #pragma unroll
    for (int q = 0; q < 6; q++) acc2[q] = (f32x4){0.f, 0.f, 0.f, 0.f};
    #pragma unroll
    for (int t = 0; t < 4; t++) {
        bf16x8 aH = *(const bf16x8*)&h_hi[arow * 136 + t * 32 + kg * 8];
        bf16x8 aL = *(const bf16x8*)&h_lo[arow * 136 + t * 32 + kg * 8];
        #pragma unroll
        for (int q = 0; q < 6; q++) {
            int j = (wave * 6 + q) * 16 + arow;
            bf16x8 bH = *(const bf16x8*)&u2t[(size_t)j * 128 + t * 32 + kg * 8];
            bf16x8 bL = *(const bf16x8*)&u2t[(size_t)D3 * D + (size_t)j * 128 + t * 32 + kg * 8];
            MFMA3(acc2[q], aH, aL, bH, bL)
        }
    }
    __syncthreads();

    #pragma unroll
    for (int q = 0; q < 6; q++) {
        int j = (wave * 6 + q) * 16 + arow;
        float bias = b2[j];
        #pragma unroll
        for (int r = 0; r < 4; r++)
            a_out[(kg * 4 + r) * 392 + j] = acc2[q][r] + bias;
    }
    __syncthreads();

    for (int t8 = tid; t8 < 16 * 128; t8 += 256) {
        int n = t8 >> 7, j = t8 & 127;
        float a0 = a_out[n * 392 + j];
        float a1 = a_out[n * 392 + 128 + j];
        float a2 = a_out[n * 392 + 256 + j];
        size_t sidx = (size_t)(n0 + n) * D + j;
        s[sidx] = s[sidx] + a2 + UV_lds[n * 132 + j] * a1;
        float vf[3];
        #pragma unroll
        for (int i = 0; i < 3; i++) {
            size_t idx = ((size_t)(n0 + n) * 3 + i) * D + j;
            vf[i] = v[idx] + U_lds[(i * 16 + n) * 132 + j] * a0;
            v[idx] = vf[i];
        }
        ushort* pvp = pv + ((size_t)(n0 + n) * 128 + j) * 6;
        pvp[3] = f2b(vf[0]);
        pvp[4] = f2b(vf[1]);
        pvp[5] = f2b(vf[2]);
    }
}

// ---------------------------------------------------------------- graph segment sum
__global__ __launch_bounds__(128) void graph_sum(
    const float* __restrict__ s, const int* __restrict__ gi, float* __restrict__ g)
{
    int d = threadIdx.x;
    int n0 = blockIdx.x * 64;
    int n1 = n0 + 64; if (n1 > NN) n1 = NN;
    if (n0 >= NN) return;
    int cur = gi[n0];
    float acc = 0.0f;
    for (int n = n0; n < n1; n++) {
        int gn = gi[n];
        if (gn != cur) { atomicAdd(&g[cur * D + d], acc); acc = 0.0f; cur = gn; }
        acc += s[n * D + d];
    }
    atomicAdd(&g[cur * D + d], acc);
}

// ---------------------------------------------------------------- readout
__global__ __launch_bounds__(128) void out_mlp(
    const float* __restrict__ g,
    const float* __restrict__ w1, const float* __restrict__ b1,
    const float* __restrict__ w2, const float* __restrict__ b2,
    float* __restrict__ out)
{
    __shared__ float gl[D];
    __shared__ float red[2];
    int j = threadIdx.x;
    int gr = blockIdx.x;
    gl[j] = g[gr * D + j];
    __syncthreads();
    float acc = b1[j];
    for (int k = 0; k < D; k++) acc += gl[k] * w1[k * D + j];
    float h = silu_f(acc) * w2[j];
    #pragma unroll
    for (int off = 32; off >= 1; off >>= 1) h += __shfl_down(h, off);
    if ((j & 63) == 0) red[j >> 6] = h;
    __syncthreads();
    if (j == 0) out[gr] = red[0] + red[1] + b2[0];
}

// ================================================================ launch
extern "C" void kernel_launch(void* const* d_in, const int* in_sizes, int n_in,
                              void* d_out, int out_size, void* d_ws, size_t ws_size,
                              hipStream_t stream)
{
    const int*   edge_src   = (const int*)  d_in[0];
    const int*   edge_dst   = (const int*)  d_in[1];
    const float* edge_vec   = (const float*)d_in[2];
    const int*   atom_types = (const int*)  d_in[3];
    const int*   node_gi    = (const int*)  d_in[4];
    const float* embedding  = (const float*)d_in[5];
    const float* phi_w1     = (const float*)d_in[6];
    const float* phi_b1     = (const float*)d_in[7];
    const float* phi_w2     = (const float*)d_in[8];
    const float* phi_b2     = (const float*)d_in[9];
    const float* filt_w     = (const float*)d_in[10];
    const float* filt_b     = (const float*)d_in[11];
    const float* upd_w1     = (const float*)d_in[12];
    const float* upd_b1     = (const float*)d_in[13];
    const float* upd_w2     = (const float*)d_in[14];
    const float* upd_b2     = (const float*)d_in[15];
    const float* U_w        = (const float*)d_in[16];
    const float* V_w        = (const float*)d_in[17];
    const float* out_w1     = (const float*)d_in[18];
    const float* out_b1     = (const float*)d_in[19];
    const float* out_w2     = (const float*)d_in[20];
    const float* out_b2     = (const float*)d_in[21];

    float* ws = (float*)d_ws;
    size_t o = 0;
    float* s_a   = ws + o; o += (size_t)NN * D;
    float* s_b   = ws + o; o += (size_t)NN * D;
    float* v_a   = ws + o; o += (size_t)NN * 3 * D;
    float* v_b   = ws + o; o += (size_t)NN * 3 * D;
    float* pv_f  = ws + o; o += (size_t)NN * 384;             // pv: [n][128][6] bf16
    float* rbf_f = ws + o; o += (size_t)NE * RBF_ROW;         // fp32, padded rows
    float* geo   = ws + o; o += (size_t)NE * 4;
    float* g     = ws + o; o += (size_t)NG * D;
    float* w1t_f = ws + o; o += (size_t)D * D;                // phi w1 hi+lo
    float* w2t_f = ws + o; o += (size_t)D3 * D;               // phi w2 hi+lo
    float* uwt_f = ws + o; o += (size_t)D * D;                // Uw^T hi+lo
    float* vwt_f = ws + o; o += (size_t)D * D;                // Vw^T hi+lo
    float* u1t_f = ws + o; o += (size_t)2 * D * D;            // upd_w1^T hi+lo
    float* u2t_f = ws + o; o += (size_t)D3 * D;               // upd_w2^T hi+lo
    int* deg     = (int*)(ws + o); o += NN;
    int* offs    = (int*)(ws + o); o += NN + 1;
    int* cursor  = (int*)(ws + o); o += NN;
    int* perm    = (int*)(ws + o); o += NN;
    int* bcount  = (int*)(ws + o); o += 64;
    int* bpos    = (int*)(ws + o); o += 64;
    int* eidb    = (int*)(ws + o); o += NE;

    ushort* pv    = (ushort*)pv_f;
    ushort* w1th  = (ushort*)w1t_f;
    ushort* w1tl  = w1th + (size_t)D * D;
    ushort* w2th  = (ushort*)w2t_f;
    ushort* w2tl  = w2th + (size_t)D3 * D;
    ushort* uwt   = (ushort*)uwt_f;
    ushort* vwt   = (ushort*)vwt_f;
    ushort* u1t   = (ushort*)u1t_f;
    ushort* u2t   = (ushort*)u2t_f;

    init_all<<<NN * D / 256, 256, 0, stream>>>(atom_types, embedding, s_a, v_a, g,
                                               deg, (uint*)pv_f, bcount);
    pack_phi_w<<<(D3 * D + 255) / 256, 256, 0, stream>>>(phi_w1, phi_w2,
                                                         w1th, w1tl, w2th, w2tl);
    pack_upd_w<<<(D3 * D + 255) / 256, 256, 0, stream>>>(U_w, V_w, upd_w1, upd_w2,
                                                         uwt, vwt, u1t, u2t);
    csr_count<<<(NE + 255) / 256, 256, 0, stream>>>(edge_dst, deg);
    csr_scan<<<1, 1024, 0, stream>>>(deg, offs, cursor);
    csr_scatter<<<(NE + 255) / 256, 256, 0, stream>>>(edge_dst, cursor, eidb);
    dbucket<<<(NN + 255) / 256, 256, 0, stream>>>(deg, bcount);
    dscan<<<1, 64, 0, stream>>>(bcount, bpos);
    dscatter<<<(NN + 255) / 256, 256, 0, stream>>>(deg, bpos, perm);
    edge_geom<<<(NE + 255) / 256, 256, 0, stream>>>(edge_vec, rbf_f, (float4*)geo);

    float *s_cur = s_a, *v_cur = v_a, *s_nxt = s_b, *v_nxt = v_b;
    for (int round = 0; round < 2; round++) {
        phi_mlp_mfma<<<(NN / 16 + 3) / 4, 256, 0, stream>>>(s_cur, w1th, w1tl, phi_b1,
                                                            w2th, w2tl, phi_b2, pv);
        node_gather<<<NN / 4, 512, 0, stream>>>(eidb, offs, perm, edge_src, pv,
                                                s_cur, v_cur, rbf_f,
                                                (const float4*)geo, filt_w, filt_b,
                                                s_nxt, v_nxt);
        node_vupd_mfma<<<NN / 16, 256, 0, stream>>>(s_nxt, v_nxt, pv,
                                                    uwt, vwt, u1t, u2t,
                                                    upd_b1, upd_b2);
        float* ts = s_cur; s_cur = s_nxt; s_nxt = ts;
        float* tv = v_cur; v_cur = v_nxt; v_nxt = tv;
    }

    graph_sum<<<(NN + 63) / 64, 128, 0, stream>>>(s_cur, node_gi, g);
    out_mlp<<<NG, 128, 0, stream>>>(g, out_w1, out_b1, out_w2, out_b2, (float*)d_out);
}

// Round 11
// 836.881 us; speedup vs baseline: 1.7844x; 1.7844x over previous
//
#include <hip/hip_runtime.h>

#define NN 20000
#define NE 320000
#define NG 64
#define D 128
#define D3 384
#define NRBF 20
#define RBF_ROW 24       // fp32 per rbf row -> 96B, 16B-aligned
#define PI_F 3.14159265358979323846f
#define RCUT 10.0f

typedef unsigned int uint;
typedef unsigned short ushort;
typedef __attribute__((ext_vector_type(8))) short bf16x8;
typedef __attribute__((ext_vector_type(4))) float f32x4;

__device__ __forceinline__ float silu_f(float x) {
    return x / (1.0f + __expf(-x));
}
__device__ __forceinline__ float b2f(ushort u) {
    return __uint_as_float(((uint)u) << 16);
}
__device__ __forceinline__ ushort f2b(float f) {
    uint u = __float_as_uint(f);
    u = u + 0x7fffu + ((u >> 16) & 1u);
    return (ushort)(u >> 16);
}
__device__ __forceinline__ float plo(uint u) { return __uint_as_float(u << 16); }
__device__ __forceinline__ float phi_(uint u) { return __uint_as_float(u & 0xffff0000u); }

#define MFMA3(acc, aH, aL, bH, bL)                                          \
    acc = __builtin_amdgcn_mfma_f32_16x16x32_bf16(aL, bH, acc, 0, 0, 0);    \
    acc = __builtin_amdgcn_mfma_f32_16x16x32_bf16(aH, bL, acc, 0, 0, 0);    \
    acc = __builtin_amdgcn_mfma_f32_16x16x32_bf16(aH, bH, acc, 0, 0, 0);

// ---------------------------------------------------------------- init
__global__ __launch_bounds__(256) void init_all(
    const int* __restrict__ atype, const float* __restrict__ emb,
    float* __restrict__ s, float* __restrict__ v, float* __restrict__ g,
    int* __restrict__ deg, uint* __restrict__ pv_u, int* __restrict__ bcount)
{
    int idx = blockIdx.x * blockDim.x + threadIdx.x;
    int stride = gridDim.x * blockDim.x;
    if (idx < NN * D) {
        int n = idx >> 7, d = idx & 127;
        s[idx] = emb[atype[n] * D + d];
    }
    if (idx < NG * D) g[idx] = 0.0f;
    if (idx < NN) deg[idx] = 0;
    if (idx < 64) bcount[idx] = 0;
    for (int i = idx; i < NN * 3 * D; i += stride) v[i] = 0.0f;
    for (int i = idx; i < NN * 384; i += stride) pv_u[i] = 0u;   // pv rows (phi+v bf16)
}

// ---------------------------------------------------------------- weight pack: phi MLP
__global__ __launch_bounds__(256) void pack_phi_w(
    const float* __restrict__ w1, const float* __restrict__ w2,
    ushort* __restrict__ w1th, ushort* __restrict__ w1tl,
    ushort* __restrict__ w2th, ushort* __restrict__ w2tl)
{
    int idx = blockIdx.x * blockDim.x + threadIdx.x;
    if (idx < D * D) {
        int j = idx >> 7, k = idx & 127;
        float x = w1[k * D + j];
        ushort h = f2b(x);
        w1th[idx] = h;
        w1tl[idx] = f2b(x - b2f(h));
    }
    if (idx < D3 * D) {
        int j = idx >> 7, k = idx & 127;
        float x = w2[k * D3 + j];
        ushort h = f2b(x);
        w2th[idx] = h;
        w2tl[idx] = f2b(x - b2f(h));
    }
}

// ---------------------------------------------------------------- weight pack: update block
__global__ __launch_bounds__(256) void pack_upd_w(
    const float* __restrict__ Uw, const float* __restrict__ Vw,
    const float* __restrict__ w1, const float* __restrict__ w2,
    ushort* __restrict__ uwt, ushort* __restrict__ vwt,
    ushort* __restrict__ u1t, ushort* __restrict__ u2t)
{
    int idx = blockIdx.x * blockDim.x + threadIdx.x;
    if (idx < D * D) {
        int j = idx >> 7, k = idx & 127;
        float x = Uw[k * D + j];
        ushort h = f2b(x);
        uwt[idx] = h; uwt[D * D + idx] = f2b(x - b2f(h));
        float y = Vw[k * D + j];
        ushort g = f2b(y);
        vwt[idx] = g; vwt[D * D + idx] = f2b(y - b2f(g));
    }
    if (idx < 2 * D * D) {
        int j = idx >> 8, k = idx & 255;
        float x = w1[k * D + j];
        ushort h = f2b(x);
        u1t[idx] = h; u1t[2 * D * D + idx] = f2b(x - b2f(h));
    }
    if (idx < D3 * D) {
        int j = idx >> 7, k = idx & 127;
        float x = w2[k * D3 + j];
        ushort h = f2b(x);
        u2t[idx] = h; u2t[D3 * D + idx] = f2b(x - b2f(h));
    }
}

// ---------------------------------------------------------------- CSR build (by dst)
__global__ __launch_bounds__(256) void csr_count(
    const int* __restrict__ dst, int* __restrict__ deg)
{
    int e = blockIdx.x * blockDim.x + threadIdx.x;
    if (e < NE) atomicAdd(&deg[dst[e]], 1);
}

__global__ __launch_bounds__(1024) void csr_scan(
    const int* __restrict__ deg, int* __restrict__ offs, int* __restrict__ cursor)
{
    __shared__ int part[1024];
    int t = threadIdx.x;
    const int per = (NN + 1023) / 1024;  // 20
    int base = t * per;
    int sum = 0;
    for (int i = 0; i < per; i++) {
        int idx = base + i;
        if (idx < NN) sum += deg[idx];
    }
    part[t] = sum;
    __syncthreads();
    for (int off = 1; off < 1024; off <<= 1) {
        int vv = (t >= off) ? part[t - off] : 0;
        __syncthreads();
        part[t] += vv;
        __syncthreads();
    }
    int run = part[t] - sum;
    for (int i = 0; i < per; i++) {
        int idx = base + i;
        if (idx < NN) {
            offs[idx] = run;
            cursor[idx] = run;
            run += deg[idx];
        }
    }
    if (t == 1023) offs[NN] = run;
}

__global__ __launch_bounds__(256) void csr_scatter(
    const int* __restrict__ dst, int* __restrict__ cursor, int* __restrict__ eid)
{
    int e = blockIdx.x * blockDim.x + threadIdx.x;
    if (e < NE) {
        int p = atomicAdd(&cursor[dst[e]], 1);
        eid[p] = e;
    }
}

// ---------------------------------------------------------------- degree sort (counting)
__global__ __launch_bounds__(256) void dbucket(
    const int* __restrict__ deg, int* __restrict__ bcount)
{
    int n = blockIdx.x * blockDim.x + threadIdx.x;
    if (n < NN) {
        int b = deg[n]; if (b > 63) b = 63;
        atomicAdd(&bcount[b], 1);
    }
}

__global__ void dscan(const int* __restrict__ bcount, int* __restrict__ bpos)
{
    if (threadIdx.x == 0) {
        int run = 0;
        for (int b = 63; b >= 0; b--) { bpos[b] = run; run += bcount[b]; }
    }
}

__global__ __launch_bounds__(256) void dscatter(
    const int* __restrict__ deg, int* __restrict__ bpos, int* __restrict__ perm)
{
    int n = blockIdx.x * blockDim.x + threadIdx.x;
    if (n < NN) {
        int b = deg[n]; if (b > 63) b = 63;
        int p = atomicAdd(&bpos[b], 1);
        perm[p] = n;
    }
}

// ---------------------------------------------------------------- edge geometry
__global__ __launch_bounds__(256) void edge_geom(
    const float* __restrict__ evec,
    float* __restrict__ rbf, float4* __restrict__ geo)
{
    int e = blockIdx.x * blockDim.x + threadIdx.x;
    if (e >= NE) return;
    float x = evec[e * 3 + 0], y = evec[e * 3 + 1], z = evec[e * 3 + 2];
    float r = sqrtf(x * x + y * y + z * z);
    float inv = 1.0f / r;
    float f = (r < RCUT) ? 0.5f * (cosf(PI_F * r / RCUT) + 1.0f) : 0.0f;
    float4 g;
    g.x = x * inv; g.y = y * inv; g.z = z * inv; g.w = f;
    geo[e] = g;
    float base = PI_F * r / RCUT;
    float sf = inv * f;
    #pragma unroll
    for (int k = 0; k < NRBF; k++) {
        rbf[(size_t)e * RBF_ROW + k] = sinf((float)(k + 1) * base) * sf;
    }
}

// ---------------------------------------------------------------- phi MLP via MFMA bf16x3
// writes phi into pv rows: pv[n][ch][slot 0..2]
__global__ __launch_bounds__(256) void phi_mlp_mfma(
    const float* __restrict__ s,
    const ushort* __restrict__ w1th, const ushort* __restrict__ w1tl,
    const float* __restrict__ b1,
    const ushort* __restrict__ w2th, const ushort* __restrict__ w2tl,
    const float* __restrict__ b2,
    ushort* __restrict__ pv)
{
    __shared__ ushort ah[4][16][136];
    __shared__ ushort al[4][16][136];
    int wave = threadIdx.x >> 6, lane = threadIdx.x & 63;
    int r0 = (blockIdx.x * 4 + wave) * 16;
    bool act = (r0 < NN);

    if (act) {
        #pragma unroll
        for (int t = 0; t < 8; t++) {
            int flat = t * 256 + lane * 4;
            int row = flat >> 7, col = flat & 127;
            float4 sv = *(const float4*)&s[(size_t)(r0 + row) * D + col];
            ushort h0 = f2b(sv.x), h1 = f2b(sv.y), h2 = f2b(sv.z), h3 = f2b(sv.w);
            ushort l0 = f2b(sv.x - b2f(h0)), l1 = f2b(sv.y - b2f(h1));
            ushort l2 = f2b(sv.z - b2f(h2)), l3 = f2b(sv.w - b2f(h3));
            uint2 ph; ph.x = (uint)h0 | ((uint)h1 << 16); ph.y = (uint)h2 | ((uint)h3 << 16);
            uint2 pl; pl.x = (uint)l0 | ((uint)l1 << 16); pl.y = (uint)l2 | ((uint)l3 << 16);
            *(uint2*)&ah[wave][row][col] = ph;
            *(uint2*)&al[wave][row][col] = pl;
        }
    }
    __syncthreads();

    int arow = lane & 15, kg = lane >> 4;
    bf16x8 aH[4], aL[4];
    if (act) {
        #pragma unroll
        for (int t = 0; t < 4; t++) {
            aH[t] = *(const bf16x8*)&ah[wave][arow][t * 32 + kg * 8];
            aL[t] = *(const bf16x8*)&al[wave][arow][t * 32 + kg * 8];
        }
    }
    __syncthreads();

    if (act) {
        #pragma unroll
        for (int jb = 0; jb < 8; jb++) {
            f32x4 acc = {0.f, 0.f, 0.f, 0.f};
            #pragma unroll
            for (int t = 0; t < 4; t++) {
                bf16x8 bh = *(const bf16x8*)&w1th[(size_t)(jb * 16 + arow) * 128 + t * 32 + kg * 8];
                bf16x8 bl = *(const bf16x8*)&w1tl[(size_t)(jb * 16 + arow) * 128 + t * 32 + kg * 8];
                acc = __builtin_amdgcn_mfma_f32_16x16x32_bf16(aH[t], bh, acc, 0, 0, 0);
                acc = __builtin_amdgcn_mfma_f32_16x16x32_bf16(aH[t], bl, acc, 0, 0, 0);
                acc = __builtin_amdgcn_mfma_f32_16x16x32_bf16(aL[t], bh, acc, 0, 0, 0);
            }
            float bias = b1[jb * 16 + arow];
            #pragma unroll
            for (int r = 0; r < 4; r++) {
                float hv = silu_f(acc[r] + bias);
                ushort hh = f2b(hv);
                ah[wave][kg * 4 + r][jb * 16 + arow] = hh;
                al[wave][kg * 4 + r][jb * 16 + arow] = f2b(hv - b2f(hh));
            }
        }
    }
    __syncthreads();

    if (act) {
        bf16x8 hH[4], hL[4];
        #pragma unroll
        for (int t = 0; t < 4; t++) {
            hH[t] = *(const bf16x8*)&ah[wave][arow][t * 32 + kg * 8];
            hL[t] = *(const bf16x8*)&al[wave][arow][t * 32 + kg * 8];
        }
        #pragma unroll
        for (int jb = 0; jb < 24; jb++) {
            f32x4 acc = {0.f, 0.f, 0.f, 0.f};
            #pragma unroll
            for (int t = 0; t < 4; t++) {
                bf16x8 bh = *(const bf16x8*)&w2th[(size_t)(jb * 16 + arow) * 128 + t * 32 + kg * 8];
                bf16x8 bl = *(const bf16x8*)&w2tl[(size_t)(jb * 16 + arow) * 128 + t * 32 + kg * 8];
                acc = __builtin_amdgcn_mfma_f32_16x16x32_bf16(hH[t], bh, acc, 0, 0, 0);
                acc = __builtin_amdgcn_mfma_f32_16x16x32_bf16(hH[t], bl, acc, 0, 0, 0);
                acc = __builtin_amdgcn_mfma_f32_16x16x32_bf16(hL[t], bh, acc, 0, 0, 0);
            }
            float bias = b2[jb * 16 + arow];
            int seg = jb >> 3;                  // phi segment 0..2 -> pv slot
            int ch  = (jb & 7) * 16 + arow;     // channel 0..127
            #pragma unroll
            for (int r = 0; r < 4; r++) {
                pv[((size_t)(r0 + kg * 4 + r) * 128 + ch) * 6 + seg] = f2b(acc[r] + bias);
            }
        }
    }
}

// ---------------------------------------------------------------- node gather
// 512 threads = 8 waves = 4 nodes x 2 channel-halves; nodes via degree-sorted perm.
// waves_per_eu(4,4): REQUIRED — 60-reg weight array spills at any higher wave
// demand (R4: 290MB scratch @(512,4)-bounds; R9: 200MB scratch @(8,8)).
// Unroll-2: both edges' scalar (eid/src/geo/rbf -> SGPR) + vector (pv dwordx3)
// loads issue at iteration top; 120 FMAs of the pair overlap the load chain.
__global__ __launch_bounds__(512)
__attribute__((amdgpu_waves_per_eu(4, 4)))
void node_gather(
    const int* __restrict__ eid, const int* __restrict__ offs,
    const int* __restrict__ perm, const int* __restrict__ src,
    const ushort* __restrict__ pv,
    const float* __restrict__ s_old, const float* __restrict__ v_old,
    const float* __restrict__ rbf, const float4* __restrict__ geo,
    const float* __restrict__ filt_w, const float* __restrict__ filt_b,
    float* __restrict__ s_new, float* __restrict__ v_new)
{
    int wave = threadIdx.x >> 6;
    int lane = threadIdx.x & 63;
    int widx = blockIdx.x * 4 + (wave >> 1);
    if (widx >= NN) return;
    int node = __builtin_amdgcn_readfirstlane(perm[widx]);
    int half = wave & 1;
    int d = half * 64 + lane;

    float wr0[NRBF], wr1[NRBF], wr2[NRBF];
    #pragma unroll
    for (int k = 0; k < NRBF; k++) {
        wr0[k] = filt_w[k * D3 + d];
        wr1[k] = filt_w[k * D3 + D + d];
        wr2[k] = filt_w[k * D3 + 2 * D + d];
    }
    float fb0 = filt_b[d], fb1 = filt_b[D + d], fb2 = filt_b[2 * D + d];
    int e0 = __builtin_amdgcn_readfirstlane(offs[node]);
    int e1 = __builtin_amdgcn_readfirstlane(offs[node + 1]);

    float acc_s = 0.f, av0 = 0.f, av1 = 0.f, av2 = 0.f;
    size_t doff = (size_t)d * 6;   // lane's ushort offset inside a pv row

    for (int i = e0; i < e1; i += 2) {
        bool hb = (i + 1 < e1);
        int ea = __builtin_amdgcn_readfirstlane(eid[i]);
        int eb = __builtin_amdgcn_readfirstlane(eid[hb ? i + 1 : i]);
        float mb = hb ? 1.0f : 0.0f;
        int sa = __builtin_amdgcn_readfirstlane(src[ea]);
        int sb = __builtin_amdgcn_readfirstlane(src[eb]);
        float4 ga = geo[ea];                              // uniform -> SGPR
        float4 gb = geo[eb];
        const float* rpa = rbf + (size_t)ea * RBF_ROW;    // uniform -> s_loads
        const float* rpb = rbf + (size_t)eb * RBF_ROW;
        uint3 pka = *(const uint3*)(pv + (size_t)sa * 768 + doff);
        uint3 pkb = *(const uint3*)(pv + (size_t)sb * 768 + doff);

        float Wa0 = ga.w * fb0, Wa1 = ga.w * fb1, Wa2 = ga.w * fb2;
        float Wb0 = gb.w * fb0, Wb1 = gb.w * fb1, Wb2 = gb.w * fb2;
        #pragma unroll
        for (int k = 0; k < NRBF; k++) {
            float ra = rpa[k], rb = rpb[k];
            Wa0 += ra * wr0[k]; Wa1 += ra * wr1[k]; Wa2 += ra * wr2[k];
            Wb0 += rb * wr0[k]; Wb1 += rb * wr1[k]; Wb2 += rb * wr2[k];
        }
        float pa0 = plo(pka.x), pa1 = phi_(pka.x), pa2 = plo(pka.y);
        float va0 = phi_(pka.y), va1 = plo(pka.z), va2 = phi_(pka.z);
        float pb0 = plo(pkb.x), pb1 = phi_(pkb.x), pb2 = plo(pkb.y);
        float vb0 = phi_(pkb.y), vb1 = plo(pkb.z), vb2 = phi_(pkb.z);

        float m1a = pa0 * Wa0, m2a = pa1 * Wa1, m3a = pa2 * Wa2;
        float m1b = pb0 * Wb0 * mb, m2b = pb1 * Wb1 * mb, m3b = pb2 * Wb2 * mb;
        acc_s += m2a + m2b;
        av0 += va0 * m1a + ga.x * m3a + vb0 * m1b + gb.x * m3b;
        av1 += va1 * m1a + ga.y * m3a + vb1 * m1b + gb.y * m3b;
        av2 += va2 * m1a + ga.z * m3a + vb2 * m1b + gb.z * m3b;
    }

    s_new[node * D + d] = s_old[node * D + d] + acc_s;
    v_new[(node * 3 + 0) * D + d] = v_old[(node * 3 + 0) * D + d] + av0;
    v_new[(node * 3 + 1) * D + d] = v_old[(node * 3 + 1) * D + d] + av1;
    v_new[(node * 3 + 2) * D + d] = v_old[(node * 3 + 2) * D + d] + av2;
}

// ---------------------------------------------------------------- fused update via MFMA bf16x3
// (R7, verified) — epilogue writes v bf16 into pv slots 3..5
__global__ __launch_bounds__(256) void node_vupd_mfma(
    float* __restrict__ s, float* __restrict__ v, ushort* __restrict__ pv,
    const ushort* __restrict__ uwt, const ushort* __restrict__ vwt,
    const ushort* __restrict__ u1t, const ushort* __restrict__ u2t,
    const float* __restrict__ b1, const float* __restrict__ b2)
{
    __shared__ __align__(16) char smem[59904];
    float*  U_lds  = (float*)(smem);             // [48][132]
    float*  UV_lds = (float*)(smem + 25344);     // [16][132]
    ushort* a_hi   = (ushort*)(smem + 33792);    // [48][136]
    ushort* a_lo   = a_hi + 48 * 136;
    ushort* x_hi   = (ushort*)(smem + 33792);    // [16][264]
    ushort* x_lo   = x_hi + 16 * 264;
    ushort* h_hi   = x_lo + 16 * 264;            // [16][136]
    ushort* h_lo   = h_hi + 16 * 136;
    float*  a_out  = (float*)(smem + 33792);     // [16][392]

    int tid = threadIdx.x;
    int wave = tid >> 6, lane = tid & 63;
    int arow = lane & 15, kg = lane >> 4;
    int n0 = blockIdx.x * 16;

    #pragma unroll
    for (int it = 0; it < 6; it++) {
        int f4 = it * 256 + tid;
        int row = f4 >> 5;
        int c4 = (f4 & 31) * 4;
        int i = row >> 4, n = row & 15;
        float4 vv = *(const float4*)&v[((size_t)(n0 + n) * 3 + i) * D + c4];
        ushort h0 = f2b(vv.x), h1 = f2b(vv.y), h2 = f2b(vv.z), h3 = f2b(vv.w);
        ushort l0 = f2b(vv.x - b2f(h0)), l1 = f2b(vv.y - b2f(h1));
        ushort l2 = f2b(vv.z - b2f(h2)), l3 = f2b(vv.w - b2f(h3));
        uint2 ph; ph.x = (uint)h0 | ((uint)h1 << 16); ph.y = (uint)h2 | ((uint)h3 << 16);
        uint2 pl; pl.x = (uint)l0 | ((uint)l1 << 16); pl.y = (uint)l2 | ((uint)l3 << 16);
        *(uint2*)&a_hi[row * 136 + c4] = ph;
        *(uint2*)&a_lo[row * 136 + c4] = pl;
    }
    __syncthreads();

    f32x4 accU[3][2], accVp[3][2];
    #pragma unroll
    for (int i = 0; i < 3; i++)
        #pragma unroll
        for (int jtl = 0; jtl < 2; jtl++) {
            accU[i][jtl] = (f32x4){0.f, 0.f, 0.f, 0.f};
            accVp[i][jtl] = (f32x4){0.f, 0.f, 0.f, 0.f};
        }
    #pragma unroll
    for (int i = 0; i < 3; i++) {
        #pragma unroll
        for (int t = 0; t < 4; t++) {
            bf16x8 aH = *(const bf16x8*)&a_hi[(i * 16 + arow) * 136 + t * 32 + kg * 8];
            bf16x8 aL = *(const bf16x8*)&a_lo[(i * 16 + arow) * 136 + t * 32 + kg * 8];
            #pragma unroll
            for (int jtl = 0; jtl < 2; jtl++) {
                int j = (wave * 2 + jtl) * 16 + arow;
                bf16x8 bH = *(const bf16x8*)&uwt[(size_t)j * 128 + t * 32 + kg * 8];
                bf16x8 bL = *(const bf16x8*)&uwt[(size_t)D * D + (size_t)j * 128 + t * 32 + kg * 8];
                MFMA3(accU[i][jtl], aH, aL, bH, bL)
                bf16x8 cH = *(const bf16x8*)&vwt[(size_t)j * 128 + t * 32 + kg * 8];
                bf16x8 cL = *(const bf16x8*)&vwt[(size_t)D * D + (size_t)j * 128 + t * 32 + kg * 8];
                MFMA3(accVp[i][jtl], aH, aL, cH, cL)
            }
        }
    }
    __syncthreads();

    #pragma unroll
    for (int jtl = 0; jtl < 2; jtl++) {
        int jcol = (wave * 2 + jtl) * 16 + arow;
        #pragma unroll
        for (int r = 0; r < 4; r++) {
            int n = kg * 4 + r;
            #pragma unroll
            for (int i = 0; i < 3; i++)
                U_lds[(i * 16 + n) * 132 + jcol] = accU[i][jtl][r];
            float uv = accU[0][jtl][r] * accVp[0][jtl][r]
                     + accU[1][jtl][r] * accVp[1][jtl][r]
                     + accU[2][jtl][r] * accVp[2][jtl][r];
            float nn = accVp[0][jtl][r] * accVp[0][jtl][r]
                     + accVp[1][jtl][r] * accVp[1][jtl][r]
                     + accVp[2][jtl][r] * accVp[2][jtl][r];
            UV_lds[n * 132 + jcol] = uv;
            float vn = sqrtf(nn);
            ushort hh = f2b(vn);
            x_hi[n * 264 + jcol] = hh;
            x_lo[n * 264 + jcol] = f2b(vn - b2f(hh));
        }
    }
    for (int t8 = tid; t8 < 16 * 128; t8 += 256) {
        int n = t8 >> 7, j = t8 & 127;
        float sv = s[(size_t)(n0 + n) * D + j];
        ushort hh = f2b(sv);
        x_hi[n * 264 + 128 + j] = hh;
        x_lo[n * 264 + 128 + j] = f2b(sv - b2f(hh));
    }
    __syncthreads();

    {
        f32x4 acc1[2];
        acc1[0] = (f32x4){0.f, 0.f, 0.f, 0.f};
        acc1[1] = (f32x4){0.f, 0.f, 0.f, 0.f};
        #pragma unroll
        for (int t = 0; t < 8; t++) {
            bf16x8 aH = *(const bf16x8*)&x_hi[arow * 264 + t * 32 + kg * 8];
            bf16x8 aL = *(const bf16x8*)&x_lo[arow * 264 + t * 32 + kg * 8];
            #pragma unroll
            for (int jtl = 0; jtl < 2; jtl++) {
                int j = (wave * 2 + jtl) * 16 + arow;
                bf16x8 bH = *(const bf16x8*)&u1t[(size_t)j * 256 + t * 32 + kg * 8];
                bf16x8 bL = *(const bf16x8*)&u1t[(size_t)2 * D * D + (size_t)j * 256 + t * 32 + kg * 8];
                MFMA3(acc1[jtl], aH, aL, bH, bL)
            }
        }
        #pragma unroll
        for (int jtl = 0; jtl < 2; jtl++) {
            int j = (wave * 2 + jtl) * 16 + arow;
            float bias = b1[j];
            #pragma unroll
            for (int r = 0; r < 4; r++) {
                int n = kg * 4 + r;
                float hv = silu_f(acc1[jtl][r] + bias);
                ushort hh = f2b(hv);
                h_hi[n * 136 + j] = hh;
                h_lo[n * 136 + j] = f2b(hv - b2f(hh));
            }
        }
    }
    __syncthreads();

    f32x4 acc2[6];
    #pragma unroll
    for (int q = 0; q < 6; q++) acc2[q] = (f32x4){0.f, 0.f, 0.f, 0.f};
    #pragma unroll
    for (int t = 0; t < 4; t++) {
        bf16x8 aH = *(const bf16x8*)&h_hi[arow * 136 + t * 32 + kg * 8];
        bf16x8 aL = *(const bf16x8*)&h_lo[arow * 136 + t * 32 + kg * 8];
        #pragma unroll
        for (int q = 0; q < 6; q++) {
            int j = (wave * 6 + q) * 16 + arow;
            bf16x8 bH = *(const bf16x8*)&u2t[(size_t)j * 128 + t * 32 + kg * 8];
            bf16x8 bL = *(const bf16x8*)&u2t[(size_t)D3 * D + (size_t)j * 128 + t * 32 + kg * 8];
            MFMA3(acc2[q], aH, aL, bH, bL)
        }
    }
    __syncthreads();

    #pragma unroll
    for (int q = 0; q < 6; q++) {
        int j = (wave * 6 + q) * 16 + arow;
        float bias = b2[j];
        #pragma unroll
        for (int r = 0; r < 4; r++)
            a_out[(kg * 4 + r) * 392 + j] = acc2[q][r] + bias;
    }
    __syncthreads();

    for (int t8 = tid; t8 < 16 * 128; t8 += 256) {
        int n = t8 >> 7, j = t8 & 127;
        float a0 = a_out[n * 392 + j];
        float a1 = a_out[n * 392 + 128 + j];
        float a2 = a_out[n * 392 + 256 + j];
        size_t sidx = (size_t)(n0 + n) * D + j;
        s[sidx] = s[sidx] + a2 + UV_lds[n * 132 + j] * a1;
        float vf[3];
        #pragma unroll
        for (int i = 0; i < 3; i++) {
            size_t idx = ((size_t)(n0 + n) * 3 + i) * D + j;
            vf[i] = v[idx] + U_lds[(i * 16 + n) * 132 + j] * a0;
            v[idx] = vf[i];
        }
        ushort* pvp = pv + ((size_t)(n0 + n) * 128 + j) * 6;
        pvp[3] = f2b(vf[0]);
        pvp[4] = f2b(vf[1]);
        pvp[5] = f2b(vf[2]);
    }
}

// ---------------------------------------------------------------- graph segment sum
__global__ __launch_bounds__(128) void graph_sum(
    const float* __restrict__ s, const int* __restrict__ gi, float* __restrict__ g)
{
    int d = threadIdx.x;
    int n0 = blockIdx.x * 64;
    int n1 = n0 + 64; if (n1 > NN) n1 = NN;
    if (n0 >= NN) return;
    int cur = gi[n0];
    float acc = 0.0f;
    for (int n = n0; n < n1; n++) {
        int gn = gi[n];
        if (gn != cur) { atomicAdd(&g[cur * D + d], acc); acc = 0.0f; cur = gn; }
        acc += s[n * D + d];
    }
    atomicAdd(&g[cur * D + d], acc);
}

// ---------------------------------------------------------------- readout
__global__ __launch_bounds__(128) void out_mlp(
    const float* __restrict__ g,
    const float* __restrict__ w1, const float* __restrict__ b1,
    const float* __restrict__ w2, const float* __restrict__ b2,
    float* __restrict__ out)
{
    __shared__ float gl[D];
    __shared__ float red[2];
    int j = threadIdx.x;
    int gr = blockIdx.x;
    gl[j] = g[gr * D + j];
    __syncthreads();
    float acc = b1[j];
    for (int k = 0; k < D; k++) acc += gl[k] * w1[k * D + j];
    float h = silu_f(acc) * w2[j];
    #pragma unroll
    for (int off = 32; off >= 1; off >>= 1) h += __shfl_down(h, off);
    if ((j & 63) == 0) red[j >> 6] = h;
    __syncthreads();
    if (j == 0) out[gr] = red[0] + red[1] + b2[0];
}

// ================================================================ launch
extern "C" void kernel_launch(void* const* d_in, const int* in_sizes, int n_in,
                              void* d_out, int out_size, void* d_ws, size_t ws_size,
                              hipStream_t stream)
{
    const int*   edge_src   = (const int*)  d_in[0];
    const int*   edge_dst   = (const int*)  d_in[1];
    const float* edge_vec   = (const float*)d_in[2];
    const int*   atom_types = (const int*)  d_in[3];
    const int*   node_gi    = (const int*)  d_in[4];
    const float* embedding  = (const float*)d_in[5];
    const float* phi_w1     = (const float*)d_in[6];
    const float* phi_b1     = (const float*)d_in[7];
    const float* phi_w2     = (const float*)d_in[8];
    const float* phi_b2     = (const float*)d_in[9];
    const float* filt_w     = (const float*)d_in[10];
    const float* filt_b     = (const float*)d_in[11];
    const float* upd_w1     = (const float*)d_in[12];
    const float* upd_b1     = (const float*)d_in[13];
    const float* upd_w2     = (const float*)d_in[14];
    const float* upd_b2     = (const float*)d_in[15];
    const float* U_w        = (const float*)d_in[16];
    const float* V_w        = (const float*)d_in[17];
    const float* out_w1     = (const float*)d_in[18];
    const float* out_b1     = (const float*)d_in[19];
    const float* out_w2     = (const float*)d_in[20];
    const float* out_b2     = (const float*)d_in[21];

    float* ws = (float*)d_ws;
    size_t o = 0;
    float* s_a   = ws + o; o += (size_t)NN * D;
    float* s_b   = ws + o; o += (size_t)NN * D;
    float* v_a   = ws + o; o += (size_t)NN * 3 * D;
    float* v_b   = ws + o; o += (size_t)NN * 3 * D;
    float* pv_f  = ws + o; o += (size_t)NN * 384;             // pv: [n][128][6] bf16
    float* rbf_f = ws + o; o += (size_t)NE * RBF_ROW;         // fp32, padded rows
    float* geo   = ws + o; o += (size_t)NE * 4;
    float* g     = ws + o; o += (size_t)NG * D;
    float* w1t_f = ws + o; o += (size_t)D * D;                // phi w1 hi+lo
    float* w2t_f = ws + o; o += (size_t)D3 * D;               // phi w2 hi+lo
    float* uwt_f = ws + o; o += (size_t)D * D;                // Uw^T hi+lo
    float* vwt_f = ws + o; o += (size_t)D * D;                // Vw^T hi+lo
    float* u1t_f = ws + o; o += (size_t)2 * D * D;            // upd_w1^T hi+lo
    float* u2t_f = ws + o; o += (size_t)D3 * D;               // upd_w2^T hi+lo
    int* deg     = (int*)(ws + o); o += NN;
    int* offs    = (int*)(ws + o); o += NN + 1;
    int* cursor  = (int*)(ws + o); o += NN;
    int* perm    = (int*)(ws + o); o += NN;
    int* bcount  = (int*)(ws + o); o += 64;
    int* bpos    = (int*)(ws + o); o += 64;
    int* eidb    = (int*)(ws + o); o += NE;

    ushort* pv    = (ushort*)pv_f;
    ushort* w1th  = (ushort*)w1t_f;
    ushort* w1tl  = w1th + (size_t)D * D;
    ushort* w2th  = (ushort*)w2t_f;
    ushort* w2tl  = w2th + (size_t)D3 * D;
    ushort* uwt   = (ushort*)uwt_f;
    ushort* vwt   = (ushort*)vwt_f;
    ushort* u1t   = (ushort*)u1t_f;
    ushort* u2t   = (ushort*)u2t_f;

    init_all<<<NN * D / 256, 256, 0, stream>>>(atom_types, embedding, s_a, v_a, g,
                                               deg, (uint*)pv_f, bcount);
    pack_phi_w<<<(D3 * D + 255) / 256, 256, 0, stream>>>(phi_w1, phi_w2,
                                                         w1th, w1tl, w2th, w2tl);
    pack_upd_w<<<(D3 * D + 255) / 256, 256, 0, stream>>>(U_w, V_w, upd_w1, upd_w2,
                                                         uwt, vwt, u1t, u2t);
    csr_count<<<(NE + 255) / 256, 256, 0, stream>>>(edge_dst, deg);
    csr_scan<<<1, 1024, 0, stream>>>(deg, offs, cursor);
    csr_scatter<<<(NE + 255) / 256, 256, 0, stream>>>(edge_dst, cursor, eidb);
    dbucket<<<(NN + 255) / 256, 256, 0, stream>>>(deg, bcount);
    dscan<<<1, 64, 0, stream>>>(bcount, bpos);
    dscatter<<<(NN + 255) / 256, 256, 0, stream>>>(deg, bpos, perm);
    edge_geom<<<(NE + 255) / 256, 256, 0, stream>>>(edge_vec, rbf_f, (float4*)geo);

    float *s_cur = s_a, *v_cur = v_a, *s_nxt = s_b, *v_nxt = v_b;
    for (int round = 0; round < 2; round++) {
        phi_mlp_mfma<<<(NN / 16 + 3) / 4, 256, 0, stream>>>(s_cur, w1th, w1tl, phi_b1,
                                                            w2th, w2tl, phi_b2, pv);
        node_gather<<<NN / 4, 512, 0, stream>>>(eidb, offs, perm, edge_src, pv,
                                                s_cur, v_cur, rbf_f,
                                                (const float4*)geo, filt_w, filt_b,
                                                s_nxt, v_nxt);
        node_vupd_mfma<<<NN / 16, 256, 0, stream>>>(s_nxt, v_nxt, pv,
                                                    uwt, vwt, u1t, u2t,
                                                    upd_b1, upd_b2);
        float* ts = s_cur; s_cur = s_nxt; s_nxt = ts;
        float* tv = v_cur; v_cur = v_nxt; v_nxt = tv;
    }

    graph_sum<<<(NN + 63) / 64, 128, 0, stream>>>(s_cur, node_gi, g);
    out_mlp<<<NG, 128, 0, stream>>>(g, out_w1, out_b1, out_w2, out_b2, (float*)d_out);
}

// Round 12
// 772.986 us; speedup vs baseline: 1.9319x; 1.0827x over previous
//
#include <hip/hip_runtime.h>

#define NN 20000
#define NE 320000
#define NG 64
#define D 128
#define D3 384
#define NRBF 20
#define RBF_ROW 24       // fp32 per rbf row -> 96B, 16B-aligned
#define PI_F 3.14159265358979323846f
#define RCUT 10.0f

typedef unsigned int uint;
typedef unsigned short ushort;
typedef __attribute__((ext_vector_type(8))) short bf16x8;
typedef __attribute__((ext_vector_type(4))) float f32x4;

__device__ __forceinline__ float silu_f(float x) {
    return x / (1.0f + __expf(-x));
}
__device__ __forceinline__ float b2f(ushort u) {
    return __uint_as_float(((uint)u) << 16);
}
__device__ __forceinline__ ushort f2b(float f) {
    uint u = __float_as_uint(f);
    u = u + 0x7fffu + ((u >> 16) & 1u);
    return (ushort)(u >> 16);
}
__device__ __forceinline__ float plo(uint u) { return __uint_as_float(u << 16); }
__device__ __forceinline__ float phi_(uint u) { return __uint_as_float(u & 0xffff0000u); }

#define MFMA3(acc, aH, aL, bH, bL)                                          \
    acc = __builtin_amdgcn_mfma_f32_16x16x32_bf16(aL, bH, acc, 0, 0, 0);    \
    acc = __builtin_amdgcn_mfma_f32_16x16x32_bf16(aH, bL, acc, 0, 0, 0);    \
    acc = __builtin_amdgcn_mfma_f32_16x16x32_bf16(aH, bH, acc, 0, 0, 0);

// ---------------------------------------------------------------- mega init
// s=emb[atype]; v=0; pv=0; g=0; deg=0; pack all MFMA weight tables (hi/lo split)
__global__ __launch_bounds__(256) void mega_init(
    const int* __restrict__ atype, const float* __restrict__ emb,
    float* __restrict__ s, float* __restrict__ v, float* __restrict__ g,
    int* __restrict__ deg, uint* __restrict__ pv_u,
    const float* __restrict__ pw1, const float* __restrict__ pw2,
    ushort* __restrict__ w1th, ushort* __restrict__ w1tl,
    ushort* __restrict__ w2th, ushort* __restrict__ w2tl,
    const float* __restrict__ Uw, const float* __restrict__ Vw,
    const float* __restrict__ uw1, const float* __restrict__ uw2,
    ushort* __restrict__ uwt, ushort* __restrict__ vwt,
    ushort* __restrict__ u1t, ushort* __restrict__ u2t)
{
    int stride = gridDim.x * blockDim.x;
    int idx0 = blockIdx.x * blockDim.x + threadIdx.x;
    for (int i = idx0; i < NN * D; i += stride)
        s[i] = emb[atype[i >> 7] * D + (i & 127)];
    for (int i = idx0; i < NN * 3 * D; i += stride) v[i] = 0.f;
    for (int i = idx0; i < NN * 384; i += stride) pv_u[i] = 0u;
    for (int i = idx0; i < NG * D; i += stride) g[i] = 0.f;
    for (int i = idx0; i < NN; i += stride) deg[i] = 0;
    for (int i = idx0; i < D * D; i += stride) {
        int j = i >> 7, k = i & 127;
        float x = pw1[k * D + j]; ushort h = f2b(x);
        w1th[i] = h; w1tl[i] = f2b(x - b2f(h));
        float a = Uw[k * D + j]; ushort ha = f2b(a);
        uwt[i] = ha; uwt[D * D + i] = f2b(a - b2f(ha));
        float b = Vw[k * D + j]; ushort hb = f2b(b);
        vwt[i] = hb; vwt[D * D + i] = f2b(b - b2f(hb));
    }
    for (int i = idx0; i < D3 * D; i += stride) {
        int j = i >> 7, k = i & 127;
        float x = pw2[k * D3 + j]; ushort h = f2b(x);
        w2th[i] = h; w2tl[i] = f2b(x - b2f(h));
        float y = uw2[k * D3 + j]; ushort hy = f2b(y);
        u2t[i] = hy; u2t[D3 * D + i] = f2b(y - b2f(hy));
    }
    for (int i = idx0; i < 2 * D * D; i += stride) {
        int j = i >> 8, k = i & 255;
        float x = uw1[k * D + j]; ushort h = f2b(x);
        u1t[i] = h; u1t[2 * D * D + i] = f2b(x - b2f(h));
    }
}

// ---------------------------------------------------------------- CSR count
__global__ __launch_bounds__(256) void csr_count(
    const int* __restrict__ dst, int* __restrict__ deg)
{
    int e = blockIdx.x * blockDim.x + threadIdx.x;
    if (e < NE) atomicAdd(&deg[dst[e]], 1);
}

// ---------------------------------------------------------------- scan (CSR offsets + degree-bucket positions)
__global__ __launch_bounds__(1024) void scan_all(
    const int* __restrict__ deg, int* __restrict__ offs,
    int* __restrict__ cursor, int* __restrict__ bpos)
{
    __shared__ int part[1024];
    __shared__ int bc[64];
    int t = threadIdx.x;
    if (t < 64) bc[t] = 0;
    __syncthreads();
    const int per = (NN + 1023) / 1024;  // 20
    int base = t * per;
    int sum = 0;
    for (int i = 0; i < per; i++) {
        int idx = base + i;
        if (idx < NN) {
            int dg = deg[idx];
            sum += dg;
            int b = dg > 63 ? 63 : dg;
            atomicAdd(&bc[b], 1);
        }
    }
    part[t] = sum;
    __syncthreads();
    for (int off = 1; off < 1024; off <<= 1) {
        int vv = (t >= off) ? part[t - off] : 0;
        __syncthreads();
        part[t] += vv;
        __syncthreads();
    }
    int run = part[t] - sum;
    for (int i = 0; i < per; i++) {
        int idx = base + i;
        if (idx < NN) {
            offs[idx] = run;
            cursor[idx] = run;
            run += deg[idx];
        }
    }
    if (t == 1023) offs[NN] = run;
    __syncthreads();
    if (t == 0) {
        int r2 = 0;
        for (int b = 63; b >= 0; b--) { bpos[b] = r2; r2 += bc[b]; }  // descending degree
    }
}

// ---------------------------------------------------------------- scatter (CSR eid + degree-sorted perm)
__global__ __launch_bounds__(256) void scatter_all(
    const int* __restrict__ dst, int* __restrict__ cursor, int* __restrict__ eid,
    const int* __restrict__ deg, int* __restrict__ bpos, int* __restrict__ perm)
{
    int i = blockIdx.x * blockDim.x + threadIdx.x;
    if (i < NE) {
        int p = atomicAdd(&cursor[dst[i]], 1);
        eid[p] = i;
    }
    if (i < NN) {
        int b = deg[i]; if (b > 63) b = 63;
        int p = atomicAdd(&bpos[b], 1);
        perm[p] = i;
    }
}

// ---------------------------------------------------------------- edge geometry
__global__ __launch_bounds__(256) void edge_geom(
    const float* __restrict__ evec,
    float* __restrict__ rbf, float4* __restrict__ geo)
{
    int e = blockIdx.x * blockDim.x + threadIdx.x;
    if (e >= NE) return;
    float x = evec[e * 3 + 0], y = evec[e * 3 + 1], z = evec[e * 3 + 2];
    float r = sqrtf(x * x + y * y + z * z);
    float inv = 1.0f / r;
    float f = (r < RCUT) ? 0.5f * (cosf(PI_F * r / RCUT) + 1.0f) : 0.0f;
    float4 g;
    g.x = x * inv; g.y = y * inv; g.z = z * inv; g.w = f;
    geo[e] = g;
    float base = PI_F * r / RCUT;
    float sf = inv * f;
    #pragma unroll
    for (int k = 0; k < NRBF; k++) {
        rbf[(size_t)e * RBF_ROW + k] = sinf((float)(k + 1) * base) * sf;
    }
}

// ---------------------------------------------------------------- phi MLP via MFMA bf16x3
// writes phi into pv rows: pv[n][ch][slot 0..2]
__global__ __launch_bounds__(256) void phi_mlp_mfma(
    const float* __restrict__ s,
    const ushort* __restrict__ w1th, const ushort* __restrict__ w1tl,
    const float* __restrict__ b1,
    const ushort* __restrict__ w2th, const ushort* __restrict__ w2tl,
    const float* __restrict__ b2,
    ushort* __restrict__ pv)
{
    __shared__ ushort ah[4][16][136];
    __shared__ ushort al[4][16][136];
    int wave = threadIdx.x >> 6, lane = threadIdx.x & 63;
    int r0 = (blockIdx.x * 4 + wave) * 16;
    bool act = (r0 < NN);

    if (act) {
        #pragma unroll
        for (int t = 0; t < 8; t++) {
            int flat = t * 256 + lane * 4;
            int row = flat >> 7, col = flat & 127;
            float4 sv = *(const float4*)&s[(size_t)(r0 + row) * D + col];
            ushort h0 = f2b(sv.x), h1 = f2b(sv.y), h2 = f2b(sv.z), h3 = f2b(sv.w);
            ushort l0 = f2b(sv.x - b2f(h0)), l1 = f2b(sv.y - b2f(h1));
            ushort l2 = f2b(sv.z - b2f(h2)), l3 = f2b(sv.w - b2f(h3));
            uint2 ph; ph.x = (uint)h0 | ((uint)h1 << 16); ph.y = (uint)h2 | ((uint)h3 << 16);
            uint2 pl; pl.x = (uint)l0 | ((uint)l1 << 16); pl.y = (uint)l2 | ((uint)l3 << 16);
            *(uint2*)&ah[wave][row][col] = ph;
            *(uint2*)&al[wave][row][col] = pl;
        }
    }
    __syncthreads();

    int arow = lane & 15, kg = lane >> 4;
    bf16x8 aH[4], aL[4];
    if (act) {
        #pragma unroll
        for (int t = 0; t < 4; t++) {
            aH[t] = *(const bf16x8*)&ah[wave][arow][t * 32 + kg * 8];
            aL[t] = *(const bf16x8*)&al[wave][arow][t * 32 + kg * 8];
        }
    }
    __syncthreads();

    if (act) {
        #pragma unroll
        for (int jb = 0; jb < 8; jb++) {
            f32x4 acc = {0.f, 0.f, 0.f, 0.f};
            #pragma unroll
            for (int t = 0; t < 4; t++) {
                bf16x8 bh = *(const bf16x8*)&w1th[(size_t)(jb * 16 + arow) * 128 + t * 32 + kg * 8];
                bf16x8 bl = *(const bf16x8*)&w1tl[(size_t)(jb * 16 + arow) * 128 + t * 32 + kg * 8];
                acc = __builtin_amdgcn_mfma_f32_16x16x32_bf16(aH[t], bh, acc, 0, 0, 0);
                acc = __builtin_amdgcn_mfma_f32_16x16x32_bf16(aH[t], bl, acc, 0, 0, 0);
                acc = __builtin_amdgcn_mfma_f32_16x16x32_bf16(aL[t], bh, acc, 0, 0, 0);
            }
            float bias = b1[jb * 16 + arow];
            #pragma unroll
            for (int r = 0; r < 4; r++) {
                float hv = silu_f(acc[r] + bias);
                ushort hh = f2b(hv);
                ah[wave][kg * 4 + r][jb * 16 + arow] = hh;
                al[wave][kg * 4 + r][jb * 16 + arow] = f2b(hv - b2f(hh));
            }
        }
    }
    __syncthreads();

    if (act) {
        bf16x8 hH[4], hL[4];
        #pragma unroll
        for (int t = 0; t < 4; t++) {
            hH[t] = *(const bf16x8*)&ah[wave][arow][t * 32 + kg * 8];
            hL[t] = *(const bf16x8*)&al[wave][arow][t * 32 + kg * 8];
        }
        #pragma unroll
        for (int jb = 0; jb < 24; jb++) {
            f32x4 acc = {0.f, 0.f, 0.f, 0.f};
            #pragma unroll
            for (int t = 0; t < 4; t++) {
                bf16x8 bh = *(const bf16x8*)&w2th[(size_t)(jb * 16 + arow) * 128 + t * 32 + kg * 8];
                bf16x8 bl = *(const bf16x8*)&w2tl[(size_t)(jb * 16 + arow) * 128 + t * 32 + kg * 8];
                acc = __builtin_amdgcn_mfma_f32_16x16x32_bf16(hH[t], bh, acc, 0, 0, 0);
                acc = __builtin_amdgcn_mfma_f32_16x16x32_bf16(hH[t], bl, acc, 0, 0, 0);
                acc = __builtin_amdgcn_mfma_f32_16x16x32_bf16(hL[t], bh, acc, 0, 0, 0);
            }
            float bias = b2[jb * 16 + arow];
            int seg = jb >> 3;                  // phi segment 0..2 -> pv slot
            int ch  = (jb & 7) * 16 + arow;     // channel 0..127
            #pragma unroll
            for (int r = 0; r < 4; r++) {
                pv[((size_t)(r0 + kg * 4 + r) * 128 + ch) * 6 + seg] = f2b(acc[r] + bias);
            }
        }
    }
}

// ---------------------------------------------------------------- node gather (R10, verified)
// waves_per_eu(4,4): REQUIRED — 60-reg weight array spills at any higher wave demand.
__global__ __launch_bounds__(512)
__attribute__((amdgpu_waves_per_eu(4, 4)))
void node_gather(
    const int* __restrict__ eid, const int* __restrict__ offs,
    const int* __restrict__ perm, const int* __restrict__ src,
    const ushort* __restrict__ pv,
    const float* __restrict__ s_old, const float* __restrict__ v_old,
    const float* __restrict__ rbf, const float4* __restrict__ geo,
    const float* __restrict__ filt_w, const float* __restrict__ filt_b,
    float* __restrict__ s_new, float* __restrict__ v_new)
{
    int wave = threadIdx.x >> 6;
    int lane = threadIdx.x & 63;
    int widx = blockIdx.x * 4 + (wave >> 1);
    if (widx >= NN) return;
    int node = __builtin_amdgcn_readfirstlane(perm[widx]);
    int half = wave & 1;
    int d = half * 64 + lane;

    float wr0[NRBF], wr1[NRBF], wr2[NRBF];
    #pragma unroll
    for (int k = 0; k < NRBF; k++) {
        wr0[k] = filt_w[k * D3 + d];
        wr1[k] = filt_w[k * D3 + D + d];
        wr2[k] = filt_w[k * D3 + 2 * D + d];
    }
    float fb0 = filt_b[d], fb1 = filt_b[D + d], fb2 = filt_b[2 * D + d];
    int e0 = __builtin_amdgcn_readfirstlane(offs[node]);
    int e1 = __builtin_amdgcn_readfirstlane(offs[node + 1]);

    float acc_s = 0.f, av0 = 0.f, av1 = 0.f, av2 = 0.f;
    size_t doff = (size_t)d * 6;   // lane's ushort offset inside a pv row

    for (int i = e0; i < e1; i += 2) {
        bool hb = (i + 1 < e1);
        int ea = __builtin_amdgcn_readfirstlane(eid[i]);
        int eb = __builtin_amdgcn_readfirstlane(eid[hb ? i + 1 : i]);
        float mb = hb ? 1.0f : 0.0f;
        int sa = __builtin_amdgcn_readfirstlane(src[ea]);
        int sb = __builtin_amdgcn_readfirstlane(src[eb]);
        float4 ga = geo[ea];                              // uniform -> SGPR
        float4 gb = geo[eb];
        const float* rpa = rbf + (size_t)ea * RBF_ROW;    // uniform -> s_loads
        const float* rpb = rbf + (size_t)eb * RBF_ROW;
        uint3 pka = *(const uint3*)(pv + (size_t)sa * 768 + doff);
        uint3 pkb = *(const uint3*)(pv + (size_t)sb * 768 + doff);

        float Wa0 = ga.w * fb0, Wa1 = ga.w * fb1, Wa2 = ga.w * fb2;
        float Wb0 = gb.w * fb0, Wb1 = gb.w * fb1, Wb2 = gb.w * fb2;
        #pragma unroll
        for (int k = 0; k < NRBF; k++) {
            float ra = rpa[k], rb = rpb[k];
            Wa0 += ra * wr0[k]; Wa1 += ra * wr1[k]; Wa2 += ra * wr2[k];
            Wb0 += rb * wr0[k]; Wb1 += rb * wr1[k]; Wb2 += rb * wr2[k];
        }
        float pa0 = plo(pka.x), pa1 = phi_(pka.x), pa2 = plo(pka.y);
        float va0 = phi_(pka.y), va1 = plo(pka.z), va2 = phi_(pka.z);
        float pb0 = plo(pkb.x), pb1 = phi_(pkb.x), pb2 = plo(pkb.y);
        float vb0 = phi_(pkb.y), vb1 = plo(pkb.z), vb2 = phi_(pkb.z);

        float m1a = pa0 * Wa0, m2a = pa1 * Wa1, m3a = pa2 * Wa2;
        float m1b = pb0 * Wb0 * mb, m2b = pb1 * Wb1 * mb, m3b = pb2 * Wb2 * mb;
        acc_s += m2a + m2b;
        av0 += va0 * m1a + ga.x * m3a + vb0 * m1b + gb.x * m3b;
        av1 += va1 * m1a + ga.y * m3a + vb1 * m1b + gb.y * m3b;
        av2 += va2 * m1a + ga.z * m3a + vb2 * m1b + gb.z * m3b;
    }

    s_new[node * D + d] = s_old[node * D + d] + acc_s;
    v_new[(node * 3 + 0) * D + d] = v_old[(node * 3 + 0) * D + d] + av0;
    v_new[(node * 3 + 1) * D + d] = v_old[(node * 3 + 1) * D + d] + av1;
    v_new[(node * 3 + 2) * D + d] = v_old[(node * 3 + 2) * D + d] + av2;
}

// ---------------------------------------------------------------- fused update via MFMA bf16x3
// LDS cut 59904 -> 47616 B (U stored bf16) => 3 blocks/CU (was 2).
// U only feeds v += U*avv; bf16 rounding of U is ~0.2% on the increment.
__global__ __launch_bounds__(256) void node_vupd_mfma(
    float* __restrict__ s, float* __restrict__ v, ushort* __restrict__ pv,
    const ushort* __restrict__ uwt, const ushort* __restrict__ vwt,
    const ushort* __restrict__ u1t, const ushort* __restrict__ u2t,
    const float* __restrict__ b1, const float* __restrict__ b2)
{
    __shared__ __align__(16) char smem[47616];
    ushort* U_lds  = (ushort*)(smem);            // [48][136] bf16
    float*  UV_lds = (float*)(smem + 13056);     // [16][132]
    ushort* a_hi   = (ushort*)(smem + 21504);    // [48][136]
    ushort* a_lo   = a_hi + 48 * 136;
    ushort* x_hi   = (ushort*)(smem + 21504);    // [16][264]
    ushort* x_lo   = x_hi + 16 * 264;
    ushort* h_hi   = x_lo + 16 * 264;            // [16][136]
    ushort* h_lo   = h_hi + 16 * 136;
    float*  a_out  = (float*)(smem + 21504);     // [16][392]

    int tid = threadIdx.x;
    int wave = tid >> 6, lane = tid & 63;
    int arow = lane & 15, kg = lane >> 4;
    int n0 = blockIdx.x * 16;

    #pragma unroll
    for (int it = 0; it < 6; it++) {
        int f4 = it * 256 + tid;
        int row = f4 >> 5;
        int c4 = (f4 & 31) * 4;
        int i = row >> 4, n = row & 15;
        float4 vv = *(const float4*)&v[((size_t)(n0 + n) * 3 + i) * D + c4];
        ushort h0 = f2b(vv.x), h1 = f2b(vv.y), h2 = f2b(vv.z), h3 = f2b(vv.w);
        ushort l0 = f2b(vv.x - b2f(h0)), l1 = f2b(vv.y - b2f(h1));
        ushort l2 = f2b(vv.z - b2f(h2)), l3 = f2b(vv.w - b2f(h3));
        uint2 ph; ph.x = (uint)h0 | ((uint)h1 << 16); ph.y = (uint)h2 | ((uint)h3 << 16);
        uint2 pl; pl.x = (uint)l0 | ((uint)l1 << 16); pl.y = (uint)l2 | ((uint)l3 << 16);
        *(uint2*)&a_hi[row * 136 + c4] = ph;
        *(uint2*)&a_lo[row * 136 + c4] = pl;
    }
    __syncthreads();

    f32x4 accU[3][2], accVp[3][2];
    #pragma unroll
    for (int i = 0; i < 3; i++)
        #pragma unroll
        for (int jtl = 0; jtl < 2; jtl++) {
            accU[i][jtl] = (f32x4){0.f, 0.f, 0.f, 0.f};
            accVp[i][jtl] = (f32x4){0.f, 0.f, 0.f, 0.f};
        }
    #pragma unroll
    for (int i = 0; i < 3; i++) {
        #pragma unroll
        for (int t = 0; t < 4; t++) {
            bf16x8 aH = *(const bf16x8*)&a_hi[(i * 16 + arow) * 136 + t * 32 + kg * 8];
            bf16x8 aL = *(const bf16x8*)&a_lo[(i * 16 + arow) * 136 + t * 32 + kg * 8];
            #pragma unroll
            for (int jtl = 0; jtl < 2; jtl++) {
                int j = (wave * 2 + jtl) * 16 + arow;
                bf16x8 bH = *(const bf16x8*)&uwt[(size_t)j * 128 + t * 32 + kg * 8];
                bf16x8 bL = *(const bf16x8*)&uwt[(size_t)D * D + (size_t)j * 128 + t * 32 + kg * 8];
                MFMA3(accU[i][jtl], aH, aL, bH, bL)
                bf16x8 cH = *(const bf16x8*)&vwt[(size_t)j * 128 + t * 32 + kg * 8];
                bf16x8 cL = *(const bf16x8*)&vwt[(size_t)D * D + (size_t)j * 128 + t * 32 + kg * 8];
                MFMA3(accVp[i][jtl], aH, aL, cH, cL)
            }
        }
    }
    __syncthreads();

    #pragma unroll
    for (int jtl = 0; jtl < 2; jtl++) {
        int jcol = (wave * 2 + jtl) * 16 + arow;
        #pragma unroll
        for (int r = 0; r < 4; r++) {
            int n = kg * 4 + r;
            #pragma unroll
            for (int i = 0; i < 3; i++)
                U_lds[(i * 16 + n) * 136 + jcol] = f2b(accU[i][jtl][r]);
            float uv = accU[0][jtl][r] * accVp[0][jtl][r]
                     + accU[1][jtl][r] * accVp[1][jtl][r]
                     + accU[2][jtl][r] * accVp[2][jtl][r];
            float nn = accVp[0][jtl][r] * accVp[0][jtl][r]
                     + accVp[1][jtl][r] * accVp[1][jtl][r]
                     + accVp[2][jtl][r] * accVp[2][jtl][r];
            UV_lds[n * 132 + jcol] = uv;
            float vn = sqrtf(nn);
            ushort hh = f2b(vn);
            x_hi[n * 264 + jcol] = hh;
            x_lo[n * 264 + jcol] = f2b(vn - b2f(hh));
        }
    }
    for (int t8 = tid; t8 < 16 * 128; t8 += 256) {
        int n = t8 >> 7, j = t8 & 127;
        float sv = s[(size_t)(n0 + n) * D + j];
        ushort hh = f2b(sv);
        x_hi[n * 264 + 128 + j] = hh;
        x_lo[n * 264 + 128 + j] = f2b(sv - b2f(hh));
    }
    __syncthreads();

    {
        f32x4 acc1[2];
        acc1[0] = (f32x4){0.f, 0.f, 0.f, 0.f};
        acc1[1] = (f32x4){0.f, 0.f, 0.f, 0.f};
        #pragma unroll
        for (int t = 0; t < 8; t++) {
            bf16x8 aH = *(const bf16x8*)&x_hi[arow * 264 + t * 32 + kg * 8];
            bf16x8 aL = *(const bf16x8*)&x_lo[arow * 264 + t * 32 + kg * 8];
            #pragma unroll
            for (int jtl = 0; jtl < 2; jtl++) {
                int j = (wave * 2 + jtl) * 16 + arow;
                bf16x8 bH = *(const bf16x8*)&u1t[(size_t)j * 256 + t * 32 + kg * 8];
                bf16x8 bL = *(const bf16x8*)&u1t[(size_t)2 * D * D + (size_t)j * 256 + t * 32 + kg * 8];
                MFMA3(acc1[jtl], aH, aL, bH, bL)
            }
        }
        #pragma unroll
        for (int jtl = 0; jtl < 2; jtl++) {
            int j = (wave * 2 + jtl) * 16 + arow;
            float bias = b1[j];
            #pragma unroll
            for (int r = 0; r < 4; r++) {
                int n = kg * 4 + r;
                float hv = silu_f(acc1[jtl][r] + bias);
                ushort hh = f2b(hv);
                h_hi[n * 136 + j] = hh;
                h_lo[n * 136 + j] = f2b(hv - b2f(hh));
            }
        }
    }
    __syncthreads();

    f32x4 acc2[6];
    #pragma unroll
    for (int q = 0; q < 6; q++) acc2[q] = (f32x4){0.f, 0.f, 0.f, 0.f};
    #pragma unroll
    for (int t = 0; t < 4; t++) {
        bf16x8 aH = *(const bf16x8*)&h_hi[arow * 136 + t * 32 + kg * 8];
        bf16x8 aL = *(const bf16x8*)&h_lo[arow * 136 + t * 32 + kg * 8];
        #pragma unroll
        for (int q = 0; q < 6; q++) {
            int j = (wave * 6 + q) * 16 + arow;
            bf16x8 bH = *(const bf16x8*)&u2t[(size_t)j * 128 + t * 32 + kg * 8];
            bf16x8 bL = *(const bf16x8*)&u2t[(size_t)D3 * D + (size_t)j * 128 + t * 32 + kg * 8];
            MFMA3(acc2[q], aH, aL, bH, bL)
        }
    }
    __syncthreads();

    #pragma unroll
    for (int q = 0; q < 6; q++) {
        int j = (wave * 6 + q) * 16 + arow;
        float bias = b2[j];
        #pragma unroll
        for (int r = 0; r < 4; r++)
            a_out[(kg * 4 + r) * 392 + j] = acc2[q][r] + bias;
    }
    __syncthreads();

    for (int t8 = tid; t8 < 16 * 128; t8 += 256) {
        int n = t8 >> 7, j = t8 & 127;
        float a0 = a_out[n * 392 + j];
        float a1 = a_out[n * 392 + 128 + j];
        float a2 = a_out[n * 392 + 256 + j];
        size_t sidx = (size_t)(n0 + n) * D + j;
        s[sidx] = s[sidx] + a2 + UV_lds[n * 132 + j] * a1;
        float vf[3];
        #pragma unroll
        for (int i = 0; i < 3; i++) {
            size_t idx = ((size_t)(n0 + n) * 3 + i) * D + j;
            vf[i] = v[idx] + b2f(U_lds[(i * 16 + n) * 136 + j]) * a0;
            v[idx] = vf[i];
        }
        ushort* pvp = pv + ((size_t)(n0 + n) * 128 + j) * 6;
        pvp[3] = f2b(vf[0]);
        pvp[4] = f2b(vf[1]);
        pvp[5] = f2b(vf[2]);
    }
}

// ---------------------------------------------------------------- graph segment sum
__global__ __launch_bounds__(128) void graph_sum(
    const float* __restrict__ s, const int* __restrict__ gi, float* __restrict__ g)
{
    int d = threadIdx.x;
    int n0 = blockIdx.x * 64;
    int n1 = n0 + 64; if (n1 > NN) n1 = NN;
    if (n0 >= NN) return;
    int cur = gi[n0];
    float acc = 0.0f;
    for (int n = n0; n < n1; n++) {
        int gn = gi[n];
        if (gn != cur) { atomicAdd(&g[cur * D + d], acc); acc = 0.0f; cur = gn; }
        acc += s[n * D + d];
    }
    atomicAdd(&g[cur * D + d], acc);
}

// ---------------------------------------------------------------- readout
__global__ __launch_bounds__(128) void out_mlp(
    const float* __restrict__ g,
    const float* __restrict__ w1, const float* __restrict__ b1,
    const float* __restrict__ w2, const float* __restrict__ b2,
    float* __restrict__ out)
{
    __shared__ float gl[D];
    __shared__ float red[2];
    int j = threadIdx.x;
    int gr = blockIdx.x;
    gl[j] = g[gr * D + j];
    __syncthreads();
    float acc = b1[j];
    for (int k = 0; k < D; k++) acc += gl[k] * w1[k * D + j];
    float h = silu_f(acc) * w2[j];
    #pragma unroll
    for (int off = 32; off >= 1; off >>= 1) h += __shfl_down(h, off);
    if ((j & 63) == 0) red[j >> 6] = h;
    __syncthreads();
    if (j == 0) out[gr] = red[0] + red[1] + b2[0];
}

// ================================================================ launch
extern "C" void kernel_launch(void* const* d_in, const int* in_sizes, int n_in,
                              void* d_out, int out_size, void* d_ws, size_t ws_size,
                              hipStream_t stream)
{
    const int*   edge_src   = (const int*)  d_in[0];
    const int*   edge_dst   = (const int*)  d_in[1];
    const float* edge_vec   = (const float*)d_in[2];
    const int*   atom_types = (const int*)  d_in[3];
    const int*   node_gi    = (const int*)  d_in[4];
    const float* embedding  = (const float*)d_in[5];
    const float* phi_w1     = (const float*)d_in[6];
    const float* phi_b1     = (const float*)d_in[7];
    const float* phi_w2     = (const float*)d_in[8];
    const float* phi_b2     = (const float*)d_in[9];
    const float* filt_w     = (const float*)d_in[10];
    const float* filt_b     = (const float*)d_in[11];
    const float* upd_w1     = (const float*)d_in[12];
    const float* upd_b1     = (const float*)d_in[13];
    const float* upd_w2     = (const float*)d_in[14];
    const float* upd_b2     = (const float*)d_in[15];
    const float* U_w        = (const float*)d_in[16];
    const float* V_w        = (const float*)d_in[17];
    const float* out_w1     = (const float*)d_in[18];
    const float* out_b1     = (const float*)d_in[19];
    const float* out_w2     = (const float*)d_in[20];
    const float* out_b2     = (const float*)d_in[21];

    float* ws = (float*)d_ws;
    size_t o = 0;
    float* s_a   = ws + o; o += (size_t)NN * D;
    float* s_b   = ws + o; o += (size_t)NN * D;
    float* v_a   = ws + o; o += (size_t)NN * 3 * D;
    float* v_b   = ws + o; o += (size_t)NN * 3 * D;
    float* pv_f  = ws + o; o += (size_t)NN * 384;             // pv: [n][128][6] bf16
    float* rbf_f = ws + o; o += (size_t)NE * RBF_ROW;         // fp32, padded rows
    float* geo   = ws + o; o += (size_t)NE * 4;
    float* g     = ws + o; o += (size_t)NG * D;
    float* w1t_f = ws + o; o += (size_t)D * D;                // phi w1 hi+lo
    float* w2t_f = ws + o; o += (size_t)D3 * D;               // phi w2 hi+lo
    float* uwt_f = ws + o; o += (size_t)D * D;                // Uw^T hi+lo
    float* vwt_f = ws + o; o += (size_t)D * D;                // Vw^T hi+lo
    float* u1t_f = ws + o; o += (size_t)2 * D * D;            // upd_w1^T hi+lo
    float* u2t_f = ws + o; o += (size_t)D3 * D;               // upd_w2^T hi+lo
    int* deg     = (int*)(ws + o); o += NN;
    int* offs    = (int*)(ws + o); o += NN + 1;
    int* cursor  = (int*)(ws + o); o += NN;
    int* perm    = (int*)(ws + o); o += NN;
    int* bpos    = (int*)(ws + o); o += 64;
    int* eidb    = (int*)(ws + o); o += NE;

    ushort* pv    = (ushort*)pv_f;
    ushort* w1th  = (ushort*)w1t_f;
    ushort* w1tl  = w1th + (size_t)D * D;
    ushort* w2th  = (ushort*)w2t_f;
    ushort* w2tl  = w2th + (size_t)D3 * D;
    ushort* uwt   = (ushort*)uwt_f;
    ushort* vwt   = (ushort*)vwt_f;
    ushort* u1t   = (ushort*)u1t_f;
    ushort* u2t   = (ushort*)u2t_f;

    mega_init<<<2048, 256, 0, stream>>>(atom_types, embedding, s_a, v_a, g, deg,
                                        (uint*)pv_f, phi_w1, phi_w2,
                                        w1th, w1tl, w2th, w2tl,
                                        U_w, V_w, upd_w1, upd_w2,
                                        uwt, vwt, u1t, u2t);
    csr_count<<<(NE + 255) / 256, 256, 0, stream>>>(edge_dst, deg);
    scan_all<<<1, 1024, 0, stream>>>(deg, offs, cursor, bpos);
    scatter_all<<<(NE + 255) / 256, 256, 0, stream>>>(edge_dst, cursor, eidb,
                                                      deg, bpos, perm);
    edge_geom<<<(NE + 255) / 256, 256, 0, stream>>>(edge_vec, rbf_f, (float4*)geo);

    float *s_cur = s_a, *v_cur = v_a, *s_nxt = s_b, *v_nxt = v_b;
    for (int round = 0; round < 2; round++) {
        phi_mlp_mfma<<<(NN / 16 + 3) / 4, 256, 0, stream>>>(s_cur, w1th, w1tl, phi_b1,
                                                            w2th, w2tl, phi_b2, pv);
        node_gather<<<NN / 4, 512, 0, stream>>>(eidb, offs, perm, edge_src, pv,
                                                s_cur, v_cur, rbf_f,
                                                (const float4*)geo, filt_w, filt_b,
                                                s_nxt, v_nxt);
        node_vupd_mfma<<<NN / 16, 256, 0, stream>>>(s_nxt, v_nxt, pv,
                                                    uwt, vwt, u1t, u2t,
                                                    upd_b1, upd_b2);
        float* ts = s_cur; s_cur = s_nxt; s_nxt = ts;
        float* tv = v_cur; v_cur = v_nxt; v_nxt = tv;
    }

    graph_sum<<<(NN + 63) / 64, 128, 0, stream>>>(s_cur, node_gi, g);
    out_mlp<<<NG, 128, 0, stream>>>(g, out_w1, out_b1, out_w2, out_b2, (float*)d_out);
}

// Round 13
// 732.500 us; speedup vs baseline: 2.0387x; 1.0553x over previous
//
#include <hip/hip_runtime.h>

#define NN 20000
#define NE 320000
#define NG 64
#define D 128
#define D3 384
#define NRBF 20
#define RBF_ROW 24       // fp32 per rbf row -> 96B, 16B-aligned
#define PI_F 3.14159265358979323846f
#define RCUT 10.0f

typedef unsigned int uint;
typedef unsigned short ushort;
typedef __attribute__((ext_vector_type(8))) short bf16x8;
typedef __attribute__((ext_vector_type(4))) float f32x4;

__device__ __forceinline__ float silu_f(float x) {
    return x / (1.0f + __expf(-x));
}
__device__ __forceinline__ float b2f(ushort u) {
    return __uint_as_float(((uint)u) << 16);
}
__device__ __forceinline__ ushort f2b(float f) {
    uint u = __float_as_uint(f);
    u = u + 0x7fffu + ((u >> 16) & 1u);
    return (ushort)(u >> 16);
}
__device__ __forceinline__ float plo(uint u) { return __uint_as_float(u << 16); }
__device__ __forceinline__ float phi_(uint u) { return __uint_as_float(u & 0xffff0000u); }

#define MFMA3(acc, aH, aL, bH, bL)                                          \
    acc = __builtin_amdgcn_mfma_f32_16x16x32_bf16(aL, bH, acc, 0, 0, 0);    \
    acc = __builtin_amdgcn_mfma_f32_16x16x32_bf16(aH, bL, acc, 0, 0, 0);    \
    acc = __builtin_amdgcn_mfma_f32_16x16x32_bf16(aH, bH, acc, 0, 0, 0);

// ---------------------------------------------------------------- mega init
__global__ __launch_bounds__(256) void mega_init(
    const int* __restrict__ atype, const float* __restrict__ emb,
    float* __restrict__ s, float* __restrict__ v, float* __restrict__ g,
    int* __restrict__ deg, uint* __restrict__ pv_u,
    const float* __restrict__ pw1, const float* __restrict__ pw2,
    ushort* __restrict__ w1th, ushort* __restrict__ w1tl,
    ushort* __restrict__ w2th, ushort* __restrict__ w2tl,
    const float* __restrict__ Uw, const float* __restrict__ Vw,
    const float* __restrict__ uw1, const float* __restrict__ uw2,
    ushort* __restrict__ uwt, ushort* __restrict__ vwt,
    ushort* __restrict__ u1t, ushort* __restrict__ u2t)
{
    int stride = gridDim.x * blockDim.x;
    int idx0 = blockIdx.x * blockDim.x + threadIdx.x;
    for (int i = idx0; i < NN * D; i += stride)
        s[i] = emb[atype[i >> 7] * D + (i & 127)];
    for (int i = idx0; i < NN * 3 * D; i += stride) v[i] = 0.f;
    for (int i = idx0; i < NN * 384; i += stride) pv_u[i] = 0u;
    for (int i = idx0; i < NG * D; i += stride) g[i] = 0.f;
    for (int i = idx0; i < NN; i += stride) deg[i] = 0;
    for (int i = idx0; i < D * D; i += stride) {
        int j = i >> 7, k = i & 127;
        float x = pw1[k * D + j]; ushort h = f2b(x);
        w1th[i] = h; w1tl[i] = f2b(x - b2f(h));
        float a = Uw[k * D + j]; ushort ha = f2b(a);
        uwt[i] = ha; uwt[D * D + i] = f2b(a - b2f(ha));
        float b = Vw[k * D + j]; ushort hb = f2b(b);
        vwt[i] = hb; vwt[D * D + i] = f2b(b - b2f(hb));
    }
    for (int i = idx0; i < D3 * D; i += stride) {
        int j = i >> 7, k = i & 127;
        float x = pw2[k * D3 + j]; ushort h = f2b(x);
        w2th[i] = h; w2tl[i] = f2b(x - b2f(h));
        float y = uw2[k * D3 + j]; ushort hy = f2b(y);
        u2t[i] = hy; u2t[D3 * D + i] = f2b(y - b2f(hy));
    }
    for (int i = idx0; i < 2 * D * D; i += stride) {
        int j = i >> 8, k = i & 255;
        float x = uw1[k * D + j]; ushort h = f2b(x);
        u1t[i] = h; u1t[2 * D * D + i] = f2b(x - b2f(h));
    }
}

// ---------------------------------------------------------------- CSR count
__global__ __launch_bounds__(256) void csr_count(
    const int* __restrict__ dst, int* __restrict__ deg)
{
    int e = blockIdx.x * blockDim.x + threadIdx.x;
    if (e < NE) atomicAdd(&deg[dst[e]], 1);
}

// ---------------------------------------------------------------- scan (CSR offsets + degree-bucket positions)
__global__ __launch_bounds__(1024) void scan_all(
    const int* __restrict__ deg, int* __restrict__ offs,
    int* __restrict__ cursor, int* __restrict__ bpos)
{
    __shared__ int part[1024];
    __shared__ int bc[64];
    int t = threadIdx.x;
    if (t < 64) bc[t] = 0;
    __syncthreads();
    const int per = (NN + 1023) / 1024;  // 20
    int base = t * per;
    int sum = 0;
    for (int i = 0; i < per; i++) {
        int idx = base + i;
        if (idx < NN) {
            int dg = deg[idx];
            sum += dg;
            int b = dg > 63 ? 63 : dg;
            atomicAdd(&bc[b], 1);
        }
    }
    part[t] = sum;
    __syncthreads();
    for (int off = 1; off < 1024; off <<= 1) {
        int vv = (t >= off) ? part[t - off] : 0;
        __syncthreads();
        part[t] += vv;
        __syncthreads();
    }
    int run = part[t] - sum;
    for (int i = 0; i < per; i++) {
        int idx = base + i;
        if (idx < NN) {
            offs[idx] = run;
            cursor[idx] = run;
            run += deg[idx];
        }
    }
    if (t == 1023) offs[NN] = run;
    __syncthreads();
    if (t == 0) {
        int r2 = 0;
        for (int b = 63; b >= 0; b--) { bpos[b] = r2; r2 += bc[b]; }  // descending degree
    }
}

// ---------------------------------------------------------------- scatter (CSR eid + degree-sorted perm)
__global__ __launch_bounds__(256) void scatter_all(
    const int* __restrict__ dst, int* __restrict__ cursor, int* __restrict__ eid,
    const int* __restrict__ deg, int* __restrict__ bpos, int* __restrict__ perm)
{
    int i = blockIdx.x * blockDim.x + threadIdx.x;
    if (i < NE) {
        int p = atomicAdd(&cursor[dst[i]], 1);
        eid[p] = i;
    }
    if (i < NN) {
        int b = deg[i]; if (b > 63) b = 63;
        int p = atomicAdd(&bpos[b], 1);
        perm[p] = i;
    }
}

// ---------------------------------------------------------------- edge geometry
__global__ __launch_bounds__(256) void edge_geom(
    const float* __restrict__ evec,
    float* __restrict__ rbf, float4* __restrict__ geo)
{
    int e = blockIdx.x * blockDim.x + threadIdx.x;
    if (e >= NE) return;
    float x = evec[e * 3 + 0], y = evec[e * 3 + 1], z = evec[e * 3 + 2];
    float r = sqrtf(x * x + y * y + z * z);
    float inv = 1.0f / r;
    float f = (r < RCUT) ? 0.5f * (cosf(PI_F * r / RCUT) + 1.0f) : 0.0f;
    float4 g;
    g.x = x * inv; g.y = y * inv; g.z = z * inv; g.w = f;
    geo[e] = g;
    float base = PI_F * r / RCUT;
    float sf = inv * f;
    #pragma unroll
    for (int k = 0; k < NRBF; k++) {
        rbf[(size_t)e * RBF_ROW + k] = sinf((float)(k + 1) * base) * sf;
    }
}

// ---------------------------------------------------------------- phi MLP via MFMA bf16x3 (round 0 only)
__global__ __launch_bounds__(256) void phi_mlp_mfma(
    const float* __restrict__ s,
    const ushort* __restrict__ w1th, const ushort* __restrict__ w1tl,
    const float* __restrict__ b1,
    const ushort* __restrict__ w2th, const ushort* __restrict__ w2tl,
    const float* __restrict__ b2,
    ushort* __restrict__ pv)
{
    __shared__ ushort ah[4][16][136];
    __shared__ ushort al[4][16][136];
    int wave = threadIdx.x >> 6, lane = threadIdx.x & 63;
    int r0 = (blockIdx.x * 4 + wave) * 16;
    bool act = (r0 < NN);

    if (act) {
        #pragma unroll
        for (int t = 0; t < 8; t++) {
            int flat = t * 256 + lane * 4;
            int row = flat >> 7, col = flat & 127;
            float4 sv = *(const float4*)&s[(size_t)(r0 + row) * D + col];
            ushort h0 = f2b(sv.x), h1 = f2b(sv.y), h2 = f2b(sv.z), h3 = f2b(sv.w);
            ushort l0 = f2b(sv.x - b2f(h0)), l1 = f2b(sv.y - b2f(h1));
            ushort l2 = f2b(sv.z - b2f(h2)), l3 = f2b(sv.w - b2f(h3));
            uint2 ph; ph.x = (uint)h0 | ((uint)h1 << 16); ph.y = (uint)h2 | ((uint)h3 << 16);
            uint2 pl; pl.x = (uint)l0 | ((uint)l1 << 16); pl.y = (uint)l2 | ((uint)l3 << 16);
            *(uint2*)&ah[wave][row][col] = ph;
            *(uint2*)&al[wave][row][col] = pl;
        }
    }
    __syncthreads();

    int arow = lane & 15, kg = lane >> 4;
    bf16x8 aH[4], aL[4];
    if (act) {
        #pragma unroll
        for (int t = 0; t < 4; t++) {
            aH[t] = *(const bf16x8*)&ah[wave][arow][t * 32 + kg * 8];
            aL[t] = *(const bf16x8*)&al[wave][arow][t * 32 + kg * 8];
        }
    }
    __syncthreads();

    if (act) {
        #pragma unroll
        for (int jb = 0; jb < 8; jb++) {
            f32x4 acc = {0.f, 0.f, 0.f, 0.f};
            #pragma unroll
            for (int t = 0; t < 4; t++) {
                bf16x8 bh = *(const bf16x8*)&w1th[(size_t)(jb * 16 + arow) * 128 + t * 32 + kg * 8];
                bf16x8 bl = *(const bf16x8*)&w1tl[(size_t)(jb * 16 + arow) * 128 + t * 32 + kg * 8];
                acc = __builtin_amdgcn_mfma_f32_16x16x32_bf16(aH[t], bh, acc, 0, 0, 0);
                acc = __builtin_amdgcn_mfma_f32_16x16x32_bf16(aH[t], bl, acc, 0, 0, 0);
                acc = __builtin_amdgcn_mfma_f32_16x16x32_bf16(aL[t], bh, acc, 0, 0, 0);
            }
            float bias = b1[jb * 16 + arow];
            #pragma unroll
            for (int r = 0; r < 4; r++) {
                float hv = silu_f(acc[r] + bias);
                ushort hh = f2b(hv);
                ah[wave][kg * 4 + r][jb * 16 + arow] = hh;
                al[wave][kg * 4 + r][jb * 16 + arow] = f2b(hv - b2f(hh));
            }
        }
    }
    __syncthreads();

    if (act) {
        bf16x8 hH[4], hL[4];
        #pragma unroll
        for (int t = 0; t < 4; t++) {
            hH[t] = *(const bf16x8*)&ah[wave][arow][t * 32 + kg * 8];
            hL[t] = *(const bf16x8*)&al[wave][arow][t * 32 + kg * 8];
        }
        #pragma unroll
        for (int jb = 0; jb < 24; jb++) {
            f32x4 acc = {0.f, 0.f, 0.f, 0.f};
            #pragma unroll
            for (int t = 0; t < 4; t++) {
                bf16x8 bh = *(const bf16x8*)&w2th[(size_t)(jb * 16 + arow) * 128 + t * 32 + kg * 8];
                bf16x8 bl = *(const bf16x8*)&w2tl[(size_t)(jb * 16 + arow) * 128 + t * 32 + kg * 8];
                acc = __builtin_amdgcn_mfma_f32_16x16x32_bf16(hH[t], bh, acc, 0, 0, 0);
                acc = __builtin_amdgcn_mfma_f32_16x16x32_bf16(hH[t], bl, acc, 0, 0, 0);
                acc = __builtin_amdgcn_mfma_f32_16x16x32_bf16(hL[t], bh, acc, 0, 0, 0);
            }
            float bias = b2[jb * 16 + arow];
            int seg = jb >> 3;
            int ch  = (jb & 7) * 16 + arow;
            #pragma unroll
            for (int r = 0; r < 4; r++) {
                pv[((size_t)(r0 + kg * 4 + r) * 128 + ch) * 6 + seg] = f2b(acc[r] + bias);
            }
        }
    }
}

// ---------------------------------------------------------------- node gather (R10, verified)
// waves_per_eu(4,4): REQUIRED — 60-reg weight array spills at any higher wave demand.
__global__ __launch_bounds__(512)
__attribute__((amdgpu_waves_per_eu(4, 4)))
void node_gather(
    const int* __restrict__ eid, const int* __restrict__ offs,
    const int* __restrict__ perm, const int* __restrict__ src,
    const ushort* __restrict__ pv,
    const float* __restrict__ s_old, const float* __restrict__ v_old,
    const float* __restrict__ rbf, const float4* __restrict__ geo,
    const float* __restrict__ filt_w, const float* __restrict__ filt_b,
    float* __restrict__ s_new, float* __restrict__ v_new)
{
    int wave = threadIdx.x >> 6;
    int lane = threadIdx.x & 63;
    int widx = blockIdx.x * 4 + (wave >> 1);
    if (widx >= NN) return;
    int node = __builtin_amdgcn_readfirstlane(perm[widx]);
    int half = wave & 1;
    int d = half * 64 + lane;

    float wr0[NRBF], wr1[NRBF], wr2[NRBF];
    #pragma unroll
    for (int k = 0; k < NRBF; k++) {
        wr0[k] = filt_w[k * D3 + d];
        wr1[k] = filt_w[k * D3 + D + d];
        wr2[k] = filt_w[k * D3 + 2 * D + d];
    }
    float fb0 = filt_b[d], fb1 = filt_b[D + d], fb2 = filt_b[2 * D + d];
    int e0 = __builtin_amdgcn_readfirstlane(offs[node]);
    int e1 = __builtin_amdgcn_readfirstlane(offs[node + 1]);

    float acc_s = 0.f, av0 = 0.f, av1 = 0.f, av2 = 0.f;
    size_t doff = (size_t)d * 6;

    for (int i = e0; i < e1; i += 2) {
        bool hb = (i + 1 < e1);
        int ea = __builtin_amdgcn_readfirstlane(eid[i]);
        int eb = __builtin_amdgcn_readfirstlane(eid[hb ? i + 1 : i]);
        float mb = hb ? 1.0f : 0.0f;
        int sa = __builtin_amdgcn_readfirstlane(src[ea]);
        int sb = __builtin_amdgcn_readfirstlane(src[eb]);
        float4 ga = geo[ea];
        float4 gb = geo[eb];
        const float* rpa = rbf + (size_t)ea * RBF_ROW;
        const float* rpb = rbf + (size_t)eb * RBF_ROW;
        uint3 pka = *(const uint3*)(pv + (size_t)sa * 768 + doff);
        uint3 pkb = *(const uint3*)(pv + (size_t)sb * 768 + doff);

        float Wa0 = ga.w * fb0, Wa1 = ga.w * fb1, Wa2 = ga.w * fb2;
        float Wb0 = gb.w * fb0, Wb1 = gb.w * fb1, Wb2 = gb.w * fb2;
        #pragma unroll
        for (int k = 0; k < NRBF; k++) {
            float ra = rpa[k], rb = rpb[k];
            Wa0 += ra * wr0[k]; Wa1 += ra * wr1[k]; Wa2 += ra * wr2[k];
            Wb0 += rb * wr0[k]; Wb1 += rb * wr1[k]; Wb2 += rb * wr2[k];
        }
        float pa0 = plo(pka.x), pa1 = phi_(pka.x), pa2 = plo(pka.y);
        float va0 = phi_(pka.y), va1 = plo(pka.z), va2 = phi_(pka.z);
        float pb0 = plo(pkb.x), pb1 = phi_(pkb.x), pb2 = plo(pkb.y);
        float vb0 = phi_(pkb.y), vb1 = plo(pkb.z), vb2 = phi_(pkb.z);

        float m1a = pa0 * Wa0, m2a = pa1 * Wa1, m3a = pa2 * Wa2;
        float m1b = pb0 * Wb0 * mb, m2b = pb1 * Wb1 * mb, m3b = pb2 * Wb2 * mb;
        acc_s += m2a + m2b;
        av0 += va0 * m1a + ga.x * m3a + vb0 * m1b + gb.x * m3b;
        av1 += va1 * m1a + ga.y * m3a + vb1 * m1b + gb.y * m3b;
        av2 += va2 * m1a + ga.z * m3a + vb2 * m1b + gb.z * m3b;
    }

    s_new[node * D + d] = s_old[node * D + d] + acc_s;
    v_new[(node * 3 + 0) * D + d] = v_old[(node * 3 + 0) * D + d] + av0;
    v_new[(node * 3 + 1) * D + d] = v_old[(node * 3 + 1) * D + d] + av1;
    v_new[(node * 3 + 2) * D + d] = v_old[(node * 3 + 2) * D + d] + av2;
}

// ---------------------------------------------------------------- fused update via MFMA bf16x3
// FUSE=true: after the update epilogue, computes next round's phi(s_new) for the
// block's 16 nodes (reusing x/h LDS regions) and writes pv slots 0..2 — removes
// the standalone phi launch + 10MB s re-read. FUSE=false (last round): skips phi
// AND pv slot 3..5 stores (no gather follows).
template<bool FUSE>
__global__ __launch_bounds__(256) void node_vupd_mfma(
    float* __restrict__ s, float* __restrict__ v, ushort* __restrict__ pv,
    const ushort* __restrict__ uwt, const ushort* __restrict__ vwt,
    const ushort* __restrict__ u1t, const ushort* __restrict__ u2t,
    const float* __restrict__ ub1, const float* __restrict__ ub2,
    const ushort* __restrict__ w1th, const ushort* __restrict__ w1tl,
    const float* __restrict__ pb1,
    const ushort* __restrict__ w2th, const ushort* __restrict__ w2tl,
    const float* __restrict__ pb2)
{
    __shared__ __align__(16) char smem[47616];
    ushort* U_lds  = (ushort*)(smem);            // [48][136] bf16
    float*  UV_lds = (float*)(smem + 13056);     // [16][132]
    ushort* a_hi   = (ushort*)(smem + 21504);    // [48][136]
    ushort* a_lo   = a_hi + 48 * 136;
    ushort* x_hi   = (ushort*)(smem + 21504);    // [16][264]
    ushort* x_lo   = x_hi + 16 * 264;
    ushort* h_hi   = x_lo + 16 * 264;            // [16][136]
    ushort* h_lo   = h_hi + 16 * 136;
    float*  a_out  = (float*)(smem + 21504);     // [16][392]

    int tid = threadIdx.x;
    int wave = tid >> 6, lane = tid & 63;
    int arow = lane & 15, kg = lane >> 4;
    int n0 = blockIdx.x * 16;

    #pragma unroll
    for (int it = 0; it < 6; it++) {
        int f4 = it * 256 + tid;
        int row = f4 >> 5;
        int c4 = (f4 & 31) * 4;
        int i = row >> 4, n = row & 15;
        float4 vv = *(const float4*)&v[((size_t)(n0 + n) * 3 + i) * D + c4];
        ushort h0 = f2b(vv.x), h1 = f2b(vv.y), h2 = f2b(vv.z), h3 = f2b(vv.w);
        ushort l0 = f2b(vv.x - b2f(h0)), l1 = f2b(vv.y - b2f(h1));
        ushort l2 = f2b(vv.z - b2f(h2)), l3 = f2b(vv.w - b2f(h3));
        uint2 ph; ph.x = (uint)h0 | ((uint)h1 << 16); ph.y = (uint)h2 | ((uint)h3 << 16);
        uint2 pl; pl.x = (uint)l0 | ((uint)l1 << 16); pl.y = (uint)l2 | ((uint)l3 << 16);
        *(uint2*)&a_hi[row * 136 + c4] = ph;
        *(uint2*)&a_lo[row * 136 + c4] = pl;
    }
    __syncthreads();

    f32x4 accU[3][2], accVp[3][2];
    #pragma unroll
    for (int i = 0; i < 3; i++)
        #pragma unroll
        for (int jtl = 0; jtl < 2; jtl++) {
            accU[i][jtl] = (f32x4){0.f, 0.f, 0.f, 0.f};
            accVp[i][jtl] = (f32x4){0.f, 0.f, 0.f, 0.f};
        }
    #pragma unroll
    for (int i = 0; i < 3; i++) {
        #pragma unroll
        for (int t = 0; t < 4; t++) {
            bf16x8 aH = *(const bf16x8*)&a_hi[(i * 16 + arow) * 136 + t * 32 + kg * 8];
            bf16x8 aL = *(const bf16x8*)&a_lo[(i * 16 + arow) * 136 + t * 32 + kg * 8];
            #pragma unroll
            for (int jtl = 0; jtl < 2; jtl++) {
                int j = (wave * 2 + jtl) * 16 + arow;
                bf16x8 bH = *(const bf16x8*)&uwt[(size_t)j * 128 + t * 32 + kg * 8];
                bf16x8 bL = *(const bf16x8*)&uwt[(size_t)D * D + (size_t)j * 128 + t * 32 + kg * 8];
                MFMA3(accU[i][jtl], aH, aL, bH, bL)
                bf16x8 cH = *(const bf16x8*)&vwt[(size_t)j * 128 + t * 32 + kg * 8];
                bf16x8 cL = *(const bf16x8*)&vwt[(size_t)D * D + (size_t)j * 128 + t * 32 + kg * 8];
                MFMA3(accVp[i][jtl], aH, aL, cH, cL)
            }
        }
    }
    __syncthreads();

    #pragma unroll
    for (int jtl = 0; jtl < 2; jtl++) {
        int jcol = (wave * 2 + jtl) * 16 + arow;
        #pragma unroll
        for (int r = 0; r < 4; r++) {
            int n = kg * 4 + r;
            #pragma unroll
            for (int i = 0; i < 3; i++)
                U_lds[(i * 16 + n) * 136 + jcol] = f2b(accU[i][jtl][r]);
            float uv = accU[0][jtl][r] * accVp[0][jtl][r]
                     + accU[1][jtl][r] * accVp[1][jtl][r]
                     + accU[2][jtl][r] * accVp[2][jtl][r];
            float nn = accVp[0][jtl][r] * accVp[0][jtl][r]
                     + accVp[1][jtl][r] * accVp[1][jtl][r]
                     + accVp[2][jtl][r] * accVp[2][jtl][r];
            UV_lds[n * 132 + jcol] = uv;
            float vn = sqrtf(nn);
            ushort hh = f2b(vn);
            x_hi[n * 264 + jcol] = hh;
            x_lo[n * 264 + jcol] = f2b(vn - b2f(hh));
        }
    }
    for (int it = 0; it < 8; it++) {
        int t8 = it * 256 + tid;
        int n = t8 >> 7, j = t8 & 127;
        float sv = s[(size_t)(n0 + n) * D + j];
        ushort hh = f2b(sv);
        x_hi[n * 264 + 128 + j] = hh;
        x_lo[n * 264 + 128 + j] = f2b(sv - b2f(hh));
    }
    __syncthreads();

    {
        f32x4 acc1[2];
        acc1[0] = (f32x4){0.f, 0.f, 0.f, 0.f};
        acc1[1] = (f32x4){0.f, 0.f, 0.f, 0.f};
        #pragma unroll
        for (int t = 0; t < 8; t++) {
            bf16x8 aH = *(const bf16x8*)&x_hi[arow * 264 + t * 32 + kg * 8];
            bf16x8 aL = *(const bf16x8*)&x_lo[arow * 264 + t * 32 + kg * 8];
            #pragma unroll
            for (int jtl = 0; jtl < 2; jtl++) {
                int j = (wave * 2 + jtl) * 16 + arow;
                bf16x8 bH = *(const bf16x8*)&u1t[(size_t)j * 256 + t * 32 + kg * 8];
                bf16x8 bL = *(const bf16x8*)&u1t[(size_t)2 * D * D + (size_t)j * 256 + t * 32 + kg * 8];
                MFMA3(acc1[jtl], aH, aL, bH, bL)
            }
        }
        #pragma unroll
        for (int jtl = 0; jtl < 2; jtl++) {
            int j = (wave * 2 + jtl) * 16 + arow;
            float bias = ub1[j];
            #pragma unroll
            for (int r = 0; r < 4; r++) {
                int n = kg * 4 + r;
                float hv = silu_f(acc1[jtl][r] + bias);
                ushort hh = f2b(hv);
                h_hi[n * 136 + j] = hh;
                h_lo[n * 136 + j] = f2b(hv - b2f(hh));
            }
        }
    }
    __syncthreads();

    f32x4 acc2[6];
    #pragma unroll
    for (int q = 0; q < 6; q++) acc2[q] = (f32x4){0.f, 0.f, 0.f, 0.f};
    #pragma unroll
    for (int t = 0; t < 4; t++) {
        bf16x8 aH = *(const bf16x8*)&h_hi[arow * 136 + t * 32 + kg * 8];
        bf16x8 aL = *(const bf16x8*)&h_lo[arow * 136 + t * 32 + kg * 8];
        #pragma unroll
        for (int q = 0; q < 6; q++) {
            int j = (wave * 6 + q) * 16 + arow;
            bf16x8 bH = *(const bf16x8*)&u2t[(size_t)j * 128 + t * 32 + kg * 8];
            bf16x8 bL = *(const bf16x8*)&u2t[(size_t)D3 * D + (size_t)j * 128 + t * 32 + kg * 8];
            MFMA3(acc2[q], aH, aL, bH, bL)
        }
    }
    __syncthreads();

    #pragma unroll
    for (int q = 0; q < 6; q++) {
        int j = (wave * 6 + q) * 16 + arow;
        float bias = ub2[j];
        #pragma unroll
        for (int r = 0; r < 4; r++)
            a_out[(kg * 4 + r) * 392 + j] = acc2[q][r] + bias;
    }
    __syncthreads();

    // ---- epilogue: s += ass + UV*asv (kept in regs); v += U*avv
    float snew_reg[8];
    #pragma unroll
    for (int it = 0; it < 8; it++) {
        int t8 = it * 256 + tid;
        int n = t8 >> 7, j = t8 & 127;
        float a0 = a_out[n * 392 + j];
        float a1 = a_out[n * 392 + 128 + j];
        float a2 = a_out[n * 392 + 256 + j];
        size_t sidx = (size_t)(n0 + n) * D + j;
        float snew = s[sidx] + a2 + UV_lds[n * 132 + j] * a1;
        s[sidx] = snew;
        snew_reg[it] = snew;
        float vf[3];
        #pragma unroll
        for (int i = 0; i < 3; i++) {
            size_t idx = ((size_t)(n0 + n) * 3 + i) * D + j;
            vf[i] = v[idx] + b2f(U_lds[(i * 16 + n) * 136 + j]) * a0;
            v[idx] = vf[i];
        }
        if (FUSE) {
            ushort* pvp = pv + ((size_t)(n0 + n) * 128 + j) * 6;
            pvp[3] = f2b(vf[0]);
            pvp[4] = f2b(vf[1]);
            pvp[5] = f2b(vf[2]);
        }
    }

    if (!FUSE) return;

    // ---- fused phi for next round: pv[slot 0..2] = phi(s_new)
    __syncthreads();   // all a_out/U/UV reads complete; x region reusable
    #pragma unroll
    for (int it = 0; it < 8; it++) {
        int t8 = it * 256 + tid;
        int n = t8 >> 7, j = t8 & 127;
        float sv = snew_reg[it];
        ushort hh = f2b(sv);
        x_hi[n * 264 + j] = hh;
        x_lo[n * 264 + j] = f2b(sv - b2f(hh));
    }
    __syncthreads();

    {
        f32x4 accp[2];
        accp[0] = (f32x4){0.f, 0.f, 0.f, 0.f};
        accp[1] = (f32x4){0.f, 0.f, 0.f, 0.f};
        #pragma unroll
        for (int t = 0; t < 4; t++) {
            bf16x8 aH = *(const bf16x8*)&x_hi[arow * 264 + t * 32 + kg * 8];
            bf16x8 aL = *(const bf16x8*)&x_lo[arow * 264 + t * 32 + kg * 8];
            #pragma unroll
            for (int jtl = 0; jtl < 2; jtl++) {
                int j = (wave * 2 + jtl) * 16 + arow;
                bf16x8 bH = *(const bf16x8*)&w1th[(size_t)j * 128 + t * 32 + kg * 8];
                bf16x8 bL = *(const bf16x8*)&w1tl[(size_t)j * 128 + t * 32 + kg * 8];
                MFMA3(accp[jtl], aH, aL, bH, bL)
            }
        }
        __syncthreads();   // x reads done before h writes (h region follows x; safe but cheap)
        #pragma unroll
        for (int jtl = 0; jtl < 2; jtl++) {
            int j = (wave * 2 + jtl) * 16 + arow;
            float bias = pb1[j];
            #pragma unroll
            for (int r = 0; r < 4; r++) {
                int n = kg * 4 + r;
                float hv = silu_f(accp[jtl][r] + bias);
                ushort hh = f2b(hv);
                h_hi[n * 136 + j] = hh;
                h_lo[n * 136 + j] = f2b(hv - b2f(hh));
            }
        }
    }
    __syncthreads();

    {
        f32x4 accq[6];
        #pragma unroll
        for (int q = 0; q < 6; q++) accq[q] = (f32x4){0.f, 0.f, 0.f, 0.f};
        #pragma unroll
        for (int t = 0; t < 4; t++) {
            bf16x8 aH = *(const bf16x8*)&h_hi[arow * 136 + t * 32 + kg * 8];
            bf16x8 aL = *(const bf16x8*)&h_lo[arow * 136 + t * 32 + kg * 8];
            #pragma unroll
            for (int q = 0; q < 6; q++) {
                int j = (wave * 6 + q) * 16 + arow;
                bf16x8 bH = *(const bf16x8*)&w2th[(size_t)j * 128 + t * 32 + kg * 8];
                bf16x8 bL = *(const bf16x8*)&w2tl[(size_t)j * 128 + t * 32 + kg * 8];
                MFMA3(accq[q], aH, aL, bH, bL)
            }
        }
        #pragma unroll
        for (int q = 0; q < 6; q++) {
            int j = (wave * 6 + q) * 16 + arow;
            float bias = pb2[j];
            int seg = j >> 7;
            int ch  = j & 127;
            #pragma unroll
            for (int r = 0; r < 4; r++) {
                pv[((size_t)(n0 + kg * 4 + r) * 128 + ch) * 6 + seg] = f2b(accq[q][r] + bias);
            }
        }
    }
}

// ---------------------------------------------------------------- graph segment sum
__global__ __launch_bounds__(128) void graph_sum(
    const float* __restrict__ s, const int* __restrict__ gi, float* __restrict__ g)
{
    int d = threadIdx.x;
    int n0 = blockIdx.x * 64;
    int n1 = n0 + 64; if (n1 > NN) n1 = NN;
    if (n0 >= NN) return;
    int cur = gi[n0];
    float acc = 0.0f;
    for (int n = n0; n < n1; n++) {
        int gn = gi[n];
        if (gn != cur) { atomicAdd(&g[cur * D + d], acc); acc = 0.0f; cur = gn; }
        acc += s[n * D + d];
    }
    atomicAdd(&g[cur * D + d], acc);
}

// ---------------------------------------------------------------- readout
__global__ __launch_bounds__(128) void out_mlp(
    const float* __restrict__ g,
    const float* __restrict__ w1, const float* __restrict__ b1,
    const float* __restrict__ w2, const float* __restrict__ b2,
    float* __restrict__ out)
{
    __shared__ float gl[D];
    __shared__ float red[2];
    int j = threadIdx.x;
    int gr = blockIdx.x;
    gl[j] = g[gr * D + j];
    __syncthreads();
    float acc = b1[j];
    for (int k = 0; k < D; k++) acc += gl[k] * w1[k * D + j];
    float h = silu_f(acc) * w2[j];
    #pragma unroll
    for (int off = 32; off >= 1; off >>= 1) h += __shfl_down(h, off);
    if ((j & 63) == 0) red[j >> 6] = h;
    __syncthreads();
    if (j == 0) out[gr] = red[0] + red[1] + b2[0];
}

// ================================================================ launch
extern "C" void kernel_launch(void* const* d_in, const int* in_sizes, int n_in,
                              void* d_out, int out_size, void* d_ws, size_t ws_size,
                              hipStream_t stream)
{
    const int*   edge_src   = (const int*)  d_in[0];
    const int*   edge_dst   = (const int*)  d_in[1];
    const float* edge_vec   = (const float*)d_in[2];
    const int*   atom_types = (const int*)  d_in[3];
    const int*   node_gi    = (const int*)  d_in[4];
    const float* embedding  = (const float*)d_in[5];
    const float* phi_w1     = (const float*)d_in[6];
    const float* phi_b1     = (const float*)d_in[7];
    const float* phi_w2     = (const float*)d_in[8];
    const float* phi_b2     = (const float*)d_in[9];
    const float* filt_w     = (const float*)d_in[10];
    const float* filt_b     = (const float*)d_in[11];
    const float* upd_w1     = (const float*)d_in[12];
    const float* upd_b1     = (const float*)d_in[13];
    const float* upd_w2     = (const float*)d_in[14];
    const float* upd_b2     = (const float*)d_in[15];
    const float* U_w        = (const float*)d_in[16];
    const float* V_w        = (const float*)d_in[17];
    const float* out_w1     = (const float*)d_in[18];
    const float* out_b1     = (const float*)d_in[19];
    const float* out_w2     = (const float*)d_in[20];
    const float* out_b2     = (const float*)d_in[21];

    float* ws = (float*)d_ws;
    size_t o = 0;
    float* s_a   = ws + o; o += (size_t)NN * D;
    float* s_b   = ws + o; o += (size_t)NN * D;
    float* v_a   = ws + o; o += (size_t)NN * 3 * D;
    float* v_b   = ws + o; o += (size_t)NN * 3 * D;
    float* pv_f  = ws + o; o += (size_t)NN * 384;             // pv: [n][128][6] bf16
    float* rbf_f = ws + o; o += (size_t)NE * RBF_ROW;         // fp32, padded rows
    float* geo   = ws + o; o += (size_t)NE * 4;
    float* g     = ws + o; o += (size_t)NG * D;
    float* w1t_f = ws + o; o += (size_t)D * D;                // phi w1 hi+lo
    float* w2t_f = ws + o; o += (size_t)D3 * D;               // phi w2 hi+lo
    float* uwt_f = ws + o; o += (size_t)D * D;                // Uw^T hi+lo
    float* vwt_f = ws + o; o += (size_t)D * D;                // Vw^T hi+lo
    float* u1t_f = ws + o; o += (size_t)2 * D * D;            // upd_w1^T hi+lo
    float* u2t_f = ws + o; o += (size_t)D3 * D;               // upd_w2^T hi+lo
    int* deg     = (int*)(ws + o); o += NN;
    int* offs    = (int*)(ws + o); o += NN + 1;
    int* cursor  = (int*)(ws + o); o += NN;
    int* perm    = (int*)(ws + o); o += NN;
    int* bpos    = (int*)(ws + o); o += 64;
    int* eidb    = (int*)(ws + o); o += NE;

    ushort* pv    = (ushort*)pv_f;
    ushort* w1th  = (ushort*)w1t_f;
    ushort* w1tl  = w1th + (size_t)D * D;
    ushort* w2th  = (ushort*)w2t_f;
    ushort* w2tl  = w2th + (size_t)D3 * D;
    ushort* uwt   = (ushort*)uwt_f;
    ushort* vwt   = (ushort*)vwt_f;
    ushort* u1t   = (ushort*)u1t_f;
    ushort* u2t   = (ushort*)u2t_f;

    mega_init<<<2048, 256, 0, stream>>>(atom_types, embedding, s_a, v_a, g, deg,
                                        (uint*)pv_f, phi_w1, phi_w2,
                                        w1th, w1tl, w2th, w2tl,
                                        U_w, V_w, upd_w1, upd_w2,
                                        uwt, vwt, u1t, u2t);
    csr_count<<<(NE + 255) / 256, 256, 0, stream>>>(edge_dst, deg);
    scan_all<<<1, 1024, 0, stream>>>(deg, offs, cursor, bpos);
    scatter_all<<<(NE + 255) / 256, 256, 0, stream>>>(edge_dst, cursor, eidb,
                                                      deg, bpos, perm);
    edge_geom<<<(NE + 255) / 256, 256, 0, stream>>>(edge_vec, rbf_f, (float4*)geo);

    // round 0
    phi_mlp_mfma<<<(NN / 16 + 3) / 4, 256, 0, stream>>>(s_a, w1th, w1tl, phi_b1,
                                                        w2th, w2tl, phi_b2, pv);
    node_gather<<<NN / 4, 512, 0, stream>>>(eidb, offs, perm, edge_src, pv,
                                            s_a, v_a, rbf_f,
                                            (const float4*)geo, filt_w, filt_b,
                                            s_b, v_b);
    node_vupd_mfma<true><<<NN / 16, 256, 0, stream>>>(s_b, v_b, pv,
                                                      uwt, vwt, u1t, u2t,
                                                      upd_b1, upd_b2,
                                                      w1th, w1tl, phi_b1,
                                                      w2th, w2tl, phi_b2);
    // round 1
    node_gather<<<NN / 4, 512, 0, stream>>>(eidb, offs, perm, edge_src, pv,
                                            s_b, v_b, rbf_f,
                                            (const float4*)geo, filt_w, filt_b,
                                            s_a, v_a);
    node_vupd_mfma<false><<<NN / 16, 256, 0, stream>>>(s_a, v_a, pv,
                                                       uwt, vwt, u1t, u2t,
                                                       upd_b1, upd_b2,
                                                       w1th, w1tl, phi_b1,
                                                       w2th, w2tl, phi_b2);

    graph_sum<<<(NN + 63) / 64, 128, 0, stream>>>(s_a, node_gi, g);
    out_mlp<<<NG, 128, 0, stream>>>(g, out_w1, out_b1, out_w2, out_b2, (float*)d_out);
}

// Round 14
// 663.354 us; speedup vs baseline: 2.2512x; 1.1042x over previous
//
#include <hip/hip_runtime.h>

#define NN 20000
#define NE 320000
#define NG 64
#define D 128
#define D3 384
#define NRBF 20
#define RBF_ROW 24       // fp32 per rbf row -> 96B, 16B-aligned
#define PI_F 3.14159265358979323846f
#define RCUT 10.0f

typedef unsigned int uint;
typedef unsigned short ushort;
typedef __attribute__((ext_vector_type(8))) short bf16x8;
typedef __attribute__((ext_vector_type(4))) float f32x4;

__device__ __forceinline__ float silu_f(float x) {
    return x / (1.0f + __expf(-x));
}
__device__ __forceinline__ float b2f(ushort u) {
    return __uint_as_float(((uint)u) << 16);
}
__device__ __forceinline__ ushort f2b(float f) {
    uint u = __float_as_uint(f);
    u = u + 0x7fffu + ((u >> 16) & 1u);
    return (ushort)(u >> 16);
}
__device__ __forceinline__ float plo(uint u) { return __uint_as_float(u << 16); }
__device__ __forceinline__ float phi_(uint u) { return __uint_as_float(u & 0xffff0000u); }

#define MFMA3(acc, aH, aL, bH, bL)                                          \
    acc = __builtin_amdgcn_mfma_f32_16x16x32_bf16(aL, bH, acc, 0, 0, 0);    \
    acc = __builtin_amdgcn_mfma_f32_16x16x32_bf16(aH, bL, acc, 0, 0, 0);    \
    acc = __builtin_amdgcn_mfma_f32_16x16x32_bf16(aH, bH, acc, 0, 0, 0);

// ---------------------------------------------------------------- mega init
// g=0; deg=0; pack all MFMA weight tables. (No s/v/pv init needed: every
// consumer is fully overwritten first — round-0 is specialized for v=0.)
__global__ __launch_bounds__(256) void mega_init(
    float* __restrict__ g, int* __restrict__ deg,
    const float* __restrict__ pw1, const float* __restrict__ pw2,
    ushort* __restrict__ w1th, ushort* __restrict__ w1tl,
    ushort* __restrict__ w2th, ushort* __restrict__ w2tl,
    const float* __restrict__ Uw, const float* __restrict__ Vw,
    const float* __restrict__ uw1, const float* __restrict__ uw2,
    ushort* __restrict__ uwt, ushort* __restrict__ vwt,
    ushort* __restrict__ u1t, ushort* __restrict__ u2t)
{
    int stride = gridDim.x * blockDim.x;
    int idx0 = blockIdx.x * blockDim.x + threadIdx.x;
    for (int i = idx0; i < NG * D; i += stride) g[i] = 0.f;
    for (int i = idx0; i < NN; i += stride) deg[i] = 0;
    for (int i = idx0; i < D * D; i += stride) {
        int j = i >> 7, k = i & 127;
        float x = pw1[k * D + j]; ushort h = f2b(x);
        w1th[i] = h; w1tl[i] = f2b(x - b2f(h));
        float a = Uw[k * D + j]; ushort ha = f2b(a);
        uwt[i] = ha; uwt[D * D + i] = f2b(a - b2f(ha));
        float b = Vw[k * D + j]; ushort hb = f2b(b);
        vwt[i] = hb; vwt[D * D + i] = f2b(b - b2f(hb));
    }
    for (int i = idx0; i < D3 * D; i += stride) {
        int j = i >> 7, k = i & 127;
        float x = pw2[k * D3 + j]; ushort h = f2b(x);
        w2th[i] = h; w2tl[i] = f2b(x - b2f(h));
        float y = uw2[k * D3 + j]; ushort hy = f2b(y);
        u2t[i] = hy; u2t[D3 * D + i] = f2b(y - b2f(hy));
    }
    for (int i = idx0; i < 2 * D * D; i += stride) {
        int j = i >> 8, k = i & 255;
        float x = uw1[k * D + j]; ushort h = f2b(x);
        u1t[i] = h; u1t[2 * D * D + i] = f2b(x - b2f(h));
    }
}

// ---------------------------------------------------------------- CSR count
__global__ __launch_bounds__(256) void csr_count(
    const int* __restrict__ dst, int* __restrict__ deg)
{
    int e = blockIdx.x * blockDim.x + threadIdx.x;
    if (e < NE) atomicAdd(&deg[dst[e]], 1);
}

// ---------------------------------------------------------------- scan (CSR offsets + degree-bucket positions)
__global__ __launch_bounds__(1024) void scan_all(
    const int* __restrict__ deg, int* __restrict__ offs,
    int* __restrict__ cursor, int* __restrict__ bpos)
{
    __shared__ int part[1024];
    __shared__ int bc[64];
    int t = threadIdx.x;
    if (t < 64) bc[t] = 0;
    __syncthreads();
    const int per = (NN + 1023) / 1024;  // 20
    int base = t * per;
    int sum = 0;
    for (int i = 0; i < per; i++) {
        int idx = base + i;
        if (idx < NN) {
            int dg = deg[idx];
            sum += dg;
            int b = dg > 63 ? 63 : dg;
            atomicAdd(&bc[b], 1);
        }
    }
    part[t] = sum;
    __syncthreads();
    for (int off = 1; off < 1024; off <<= 1) {
        int vv = (t >= off) ? part[t - off] : 0;
        __syncthreads();
        part[t] += vv;
        __syncthreads();
    }
    int run = part[t] - sum;
    for (int i = 0; i < per; i++) {
        int idx = base + i;
        if (idx < NN) {
            offs[idx] = run;
            cursor[idx] = run;
            run += deg[idx];
        }
    }
    if (t == 1023) offs[NN] = run;
    __syncthreads();
    if (t == 0) {
        int r2 = 0;
        for (int b = 63; b >= 0; b--) { bpos[b] = r2; r2 += bc[b]; }  // descending degree
    }
}

// ---------------------------------------------------------------- scatter (CSR eid + degree-sorted perm)
__global__ __launch_bounds__(256) void scatter_all(
    const int* __restrict__ dst, int* __restrict__ cursor, int* __restrict__ eid,
    const int* __restrict__ deg, int* __restrict__ bpos, int* __restrict__ perm)
{
    int i = blockIdx.x * blockDim.x + threadIdx.x;
    if (i < NE) {
        int p = atomicAdd(&cursor[dst[i]], 1);
        eid[p] = i;
    }
    if (i < NN) {
        int b = deg[i]; if (b > 63) b = 63;
        int p = atomicAdd(&bpos[b], 1);
        perm[p] = i;
    }
}

// ---------------------------------------------------------------- edge geometry
__global__ __launch_bounds__(256) void edge_geom(
    const float* __restrict__ evec,
    float* __restrict__ rbf, float4* __restrict__ geo)
{
    int e = blockIdx.x * blockDim.x + threadIdx.x;
    if (e >= NE) return;
    float x = evec[e * 3 + 0], y = evec[e * 3 + 1], z = evec[e * 3 + 2];
    float r = sqrtf(x * x + y * y + z * z);
    float inv = 1.0f / r;
    float f = (r < RCUT) ? 0.5f * (cosf(PI_F * r / RCUT) + 1.0f) : 0.0f;
    float4 g;
    g.x = x * inv; g.y = y * inv; g.z = z * inv; g.w = f;
    geo[e] = g;
    float base = PI_F * r / RCUT;
    float sf = inv * f;
    #pragma unroll
    for (int k = 0; k < NRBF; k++) {
        rbf[(size_t)e * RBF_ROW + k] = sinf((float)(k + 1) * base) * sf;
    }
}

// ---------------------------------------------------------------- phi table (round 0)
// Only 10 distinct s rows at round 0 (s = emb[atype]); phi needed only for
// m2/m3 (m1 multiplies v=0). ptab[t][d] = pack(bf16(phi1), bf16(phi2)).
__global__ __launch_bounds__(128) void phi10(
    const float* __restrict__ emb,
    const float* __restrict__ w1, const float* __restrict__ b1,
    const float* __restrict__ w2, const float* __restrict__ b2,
    uint* __restrict__ ptab)
{
    __shared__ float el[D];
    __shared__ float hl[D];
    int t = blockIdx.x, j = threadIdx.x;
    el[j] = emb[t * D + j];
    __syncthreads();
    float acc = b1[j];
    for (int k = 0; k < D; k++) acc += el[k] * w1[k * D + j];
    hl[j] = silu_f(acc);
    __syncthreads();
    float a1 = b2[D + j], a2 = b2[2 * D + j];
    for (int k = 0; k < D; k++) {
        float h = hl[k];
        a1 += h * w2[k * D3 + D + j];
        a2 += h * w2[k * D3 + 2 * D + j];
    }
    ptab[t * D + j] = (uint)f2b(a1) | ((uint)f2b(a2) << 16);
}

// ---------------------------------------------------------------- node gather round 0 (v=0 specialization)
// m1 path exactly 0 (v_old=0). phi via 5KB L1 table keyed by atype[src].
// s_old read directly from emb. Only W1/W2 recomputed (40 FMAs/edge).
__global__ __launch_bounds__(512)
__attribute__((amdgpu_waves_per_eu(4, 4)))
void node_gather_r0(
    const int* __restrict__ eid, const int* __restrict__ offs,
    const int* __restrict__ perm, const int* __restrict__ src,
    const int* __restrict__ atype, const float* __restrict__ emb,
    const uint* __restrict__ ptab,
    const float* __restrict__ rbf, const float4* __restrict__ geo,
    const float* __restrict__ filt_w, const float* __restrict__ filt_b,
    float* __restrict__ s_new, float* __restrict__ v_new)
{
    int wave = threadIdx.x >> 6;
    int lane = threadIdx.x & 63;
    int widx = blockIdx.x * 4 + (wave >> 1);
    if (widx >= NN) return;
    int node = __builtin_amdgcn_readfirstlane(perm[widx]);
    int half = wave & 1;
    int d = half * 64 + lane;

    float wr1[NRBF], wr2[NRBF];
    #pragma unroll
    for (int k = 0; k < NRBF; k++) {
        wr1[k] = filt_w[k * D3 + D + d];
        wr2[k] = filt_w[k * D3 + 2 * D + d];
    }
    float fb1 = filt_b[D + d], fb2 = filt_b[2 * D + d];
    int e0 = __builtin_amdgcn_readfirstlane(offs[node]);
    int e1 = __builtin_amdgcn_readfirstlane(offs[node + 1]);

    float acc_s = 0.f, av0 = 0.f, av1 = 0.f, av2 = 0.f;

    for (int i = e0; i < e1; i += 2) {
        bool hb = (i + 1 < e1);
        int ea = __builtin_amdgcn_readfirstlane(eid[i]);
        int eb = __builtin_amdgcn_readfirstlane(eid[hb ? i + 1 : i]);
        float mb = hb ? 1.0f : 0.0f;
        int sa = __builtin_amdgcn_readfirstlane(src[ea]);
        int sb = __builtin_amdgcn_readfirstlane(src[eb]);
        int ta = __builtin_amdgcn_readfirstlane(atype[sa]);
        int tb = __builtin_amdgcn_readfirstlane(atype[sb]);
        float4 ga = geo[ea];
        float4 gb = geo[eb];
        const float* rpa = rbf + (size_t)ea * RBF_ROW;
        const float* rpb = rbf + (size_t)eb * RBF_ROW;
        uint pka = ptab[ta * D + d];
        uint pkb = ptab[tb * D + d];

        float Wa1 = ga.w * fb1, Wa2 = ga.w * fb2;
        float Wb1 = gb.w * fb1, Wb2 = gb.w * fb2;
        #pragma unroll
        for (int k = 0; k < NRBF; k++) {
            float ra = rpa[k], rb = rpb[k];
            Wa1 += ra * wr1[k]; Wa2 += ra * wr2[k];
            Wb1 += rb * wr1[k]; Wb2 += rb * wr2[k];
        }
        float pa1 = plo(pka), pa2 = phi_(pka);
        float pb1 = plo(pkb), pb2 = phi_(pkb);

        float m2a = pa1 * Wa1, m3a = pa2 * Wa2;
        float m2b = pb1 * Wb1 * mb, m3b = pb2 * Wb2 * mb;
        acc_s += m2a + m2b;
        av0 += ga.x * m3a + gb.x * m3b;
        av1 += ga.y * m3a + gb.y * m3b;
        av2 += ga.z * m3a + gb.z * m3b;
    }

    int tn = __builtin_amdgcn_readfirstlane(atype[node]);
    s_new[node * D + d] = emb[tn * D + d] + acc_s;
    v_new[(node * 3 + 0) * D + d] = av0;
    v_new[(node * 3 + 1) * D + d] = av1;
    v_new[(node * 3 + 2) * D + d] = av2;
}

// ---------------------------------------------------------------- node gather (round 1; R10 verified)
// waves_per_eu(4,4): REQUIRED — 60-reg weight array spills at any higher wave demand.
__global__ __launch_bounds__(512)
__attribute__((amdgpu_waves_per_eu(4, 4)))
void node_gather(
    const int* __restrict__ eid, const int* __restrict__ offs,
    const int* __restrict__ perm, const int* __restrict__ src,
    const ushort* __restrict__ pv,
    const float* __restrict__ s_old, const float* __restrict__ v_old,
    const float* __restrict__ rbf, const float4* __restrict__ geo,
    const float* __restrict__ filt_w, const float* __restrict__ filt_b,
    float* __restrict__ s_new, float* __restrict__ v_new)
{
    int wave = threadIdx.x >> 6;
    int lane = threadIdx.x & 63;
    int widx = blockIdx.x * 4 + (wave >> 1);
    if (widx >= NN) return;
    int node = __builtin_amdgcn_readfirstlane(perm[widx]);
    int half = wave & 1;
    int d = half * 64 + lane;

    float wr0[NRBF], wr1[NRBF], wr2[NRBF];
    #pragma unroll
    for (int k = 0; k < NRBF; k++) {
        wr0[k] = filt_w[k * D3 + d];
        wr1[k] = filt_w[k * D3 + D + d];
        wr2[k] = filt_w[k * D3 + 2 * D + d];
    }
    float fb0 = filt_b[d], fb1 = filt_b[D + d], fb2 = filt_b[2 * D + d];
    int e0 = __builtin_amdgcn_readfirstlane(offs[node]);
    int e1 = __builtin_amdgcn_readfirstlane(offs[node + 1]);

    float acc_s = 0.f, av0 = 0.f, av1 = 0.f, av2 = 0.f;
    size_t doff = (size_t)d * 6;

    for (int i = e0; i < e1; i += 2) {
        bool hb = (i + 1 < e1);
        int ea = __builtin_amdgcn_readfirstlane(eid[i]);
        int eb = __builtin_amdgcn_readfirstlane(eid[hb ? i + 1 : i]);
        float mb = hb ? 1.0f : 0.0f;
        int sa = __builtin_amdgcn_readfirstlane(src[ea]);
        int sb = __builtin_amdgcn_readfirstlane(src[eb]);
        float4 ga = geo[ea];
        float4 gb = geo[eb];
        const float* rpa = rbf + (size_t)ea * RBF_ROW;
        const float* rpb = rbf + (size_t)eb * RBF_ROW;
        uint3 pka = *(const uint3*)(pv + (size_t)sa * 768 + doff);
        uint3 pkb = *(const uint3*)(pv + (size_t)sb * 768 + doff);

        float Wa0 = ga.w * fb0, Wa1 = ga.w * fb1, Wa2 = ga.w * fb2;
        float Wb0 = gb.w * fb0, Wb1 = gb.w * fb1, Wb2 = gb.w * fb2;
        #pragma unroll
        for (int k = 0; k < NRBF; k++) {
            float ra = rpa[k], rb = rpb[k];
            Wa0 += ra * wr0[k]; Wa1 += ra * wr1[k]; Wa2 += ra * wr2[k];
            Wb0 += rb * wr0[k]; Wb1 += rb * wr1[k]; Wb2 += rb * wr2[k];
        }
        float pa0 = plo(pka.x), pa1 = phi_(pka.x), pa2 = plo(pka.y);
        float va0 = phi_(pka.y), va1 = plo(pka.z), va2 = phi_(pka.z);
        float pb0 = plo(pkb.x), pb1 = phi_(pkb.x), pb2 = plo(pkb.y);
        float vb0 = phi_(pkb.y), vb1 = plo(pkb.z), vb2 = phi_(pkb.z);

        float m1a = pa0 * Wa0, m2a = pa1 * Wa1, m3a = pa2 * Wa2;
        float m1b = pb0 * Wb0 * mb, m2b = pb1 * Wb1 * mb, m3b = pb2 * Wb2 * mb;
        acc_s += m2a + m2b;
        av0 += va0 * m1a + ga.x * m3a + vb0 * m1b + gb.x * m3b;
        av1 += va1 * m1a + ga.y * m3a + vb1 * m1b + gb.y * m3b;
        av2 += va2 * m1a + ga.z * m3a + vb2 * m1b + gb.z * m3b;
    }

    s_new[node * D + d] = s_old[node * D + d] + acc_s;
    v_new[(node * 3 + 0) * D + d] = v_old[(node * 3 + 0) * D + d] + av0;
    v_new[(node * 3 + 1) * D + d] = v_old[(node * 3 + 1) * D + d] + av1;
    v_new[(node * 3 + 2) * D + d] = v_old[(node * 3 + 2) * D + d] + av2;
}

// ---------------------------------------------------------------- fused update via MFMA bf16x3
// FUSE=true: appends next round's phi(s_new) -> pv slots 0..2 (and v -> 3..5).
// FUSE=false (last round): skips both.
template<bool FUSE>
__global__ __launch_bounds__(256) void node_vupd_mfma(
    float* __restrict__ s, float* __restrict__ v, ushort* __restrict__ pv,
    const ushort* __restrict__ uwt, const ushort* __restrict__ vwt,
    const ushort* __restrict__ u1t, const ushort* __restrict__ u2t,
    const float* __restrict__ ub1, const float* __restrict__ ub2,
    const ushort* __restrict__ w1th, const ushort* __restrict__ w1tl,
    const float* __restrict__ pb1,
    const ushort* __restrict__ w2th, const ushort* __restrict__ w2tl,
    const float* __restrict__ pb2)
{
    __shared__ __align__(16) char smem[47616];
    ushort* U_lds  = (ushort*)(smem);            // [48][136] bf16
    float*  UV_lds = (float*)(smem + 13056);     // [16][132]
    ushort* a_hi   = (ushort*)(smem + 21504);    // [48][136]
    ushort* a_lo   = a_hi + 48 * 136;
    ushort* x_hi   = (ushort*)(smem + 21504);    // [16][264]
    ushort* x_lo   = x_hi + 16 * 264;
    ushort* h_hi   = x_lo + 16 * 264;            // [16][136]
    ushort* h_lo   = h_hi + 16 * 136;
    float*  a_out  = (float*)(smem + 21504);     // [16][392]

    int tid = threadIdx.x;
    int wave = tid >> 6, lane = tid & 63;
    int arow = lane & 15, kg = lane >> 4;
    int n0 = blockIdx.x * 16;

    #pragma unroll
    for (int it = 0; it < 6; it++) {
        int f4 = it * 256 + tid;
        int row = f4 >> 5;
        int c4 = (f4 & 31) * 4;
        int i = row >> 4, n = row & 15;
        float4 vv = *(const float4*)&v[((size_t)(n0 + n) * 3 + i) * D + c4];
        ushort h0 = f2b(vv.x), h1 = f2b(vv.y), h2 = f2b(vv.z), h3 = f2b(vv.w);
        ushort l0 = f2b(vv.x - b2f(h0)), l1 = f2b(vv.y - b2f(h1));
        ushort l2 = f2b(vv.z - b2f(h2)), l3 = f2b(vv.w - b2f(h3));
        uint2 ph; ph.x = (uint)h0 | ((uint)h1 << 16); ph.y = (uint)h2 | ((uint)h3 << 16);
        uint2 pl; pl.x = (uint)l0 | ((uint)l1 << 16); pl.y = (uint)l2 | ((uint)l3 << 16);
        *(uint2*)&a_hi[row * 136 + c4] = ph;
        *(uint2*)&a_lo[row * 136 + c4] = pl;
    }
    __syncthreads();

    f32x4 accU[3][2], accVp[3][2];
    #pragma unroll
    for (int i = 0; i < 3; i++)
        #pragma unroll
        for (int jtl = 0; jtl < 2; jtl++) {
            accU[i][jtl] = (f32x4){0.f, 0.f, 0.f, 0.f};
            accVp[i][jtl] = (f32x4){0.f, 0.f, 0.f, 0.f};
        }
    #pragma unroll
    for (int i = 0; i < 3; i++) {
        #pragma unroll
        for (int t = 0; t < 4; t++) {
            bf16x8 aH = *(const bf16x8*)&a_hi[(i * 16 + arow) * 136 + t * 32 + kg * 8];
            bf16x8 aL = *(const bf16x8*)&a_lo[(i * 16 + arow) * 136 + t * 32 + kg * 8];
            #pragma unroll
            for (int jtl = 0; jtl < 2; jtl++) {
                int j = (wave * 2 + jtl) * 16 + arow;
                bf16x8 bH = *(const bf16x8*)&uwt[(size_t)j * 128 + t * 32 + kg * 8];
                bf16x8 bL = *(const bf16x8*)&uwt[(size_t)D * D + (size_t)j * 128 + t * 32 + kg * 8];
                MFMA3(accU[i][jtl], aH, aL, bH, bL)
                bf16x8 cH = *(const bf16x8*)&vwt[(size_t)j * 128 + t * 32 + kg * 8];
                bf16x8 cL = *(const bf16x8*)&vwt[(size_t)D * D + (size_t)j * 128 + t * 32 + kg * 8];
                MFMA3(accVp[i][jtl], aH, aL, cH, cL)
            }
        }
    }
    __syncthreads();

    #pragma unroll
    for (int jtl = 0; jtl < 2; jtl++) {
        int jcol = (wave * 2 + jtl) * 16 + arow;
        #pragma unroll
        for (int r = 0; r < 4; r++) {
            int n = kg * 4 + r;
            #pragma unroll
            for (int i = 0; i < 3; i++)
                U_lds[(i * 16 + n) * 136 + jcol] = f2b(accU[i][jtl][r]);
            float uv = accU[0][jtl][r] * accVp[0][jtl][r]
                     + accU[1][jtl][r] * accVp[1][jtl][r]
                     + accU[2][jtl][r] * accVp[2][jtl][r];
            float nn = accVp[0][jtl][r] * accVp[0][jtl][r]
                     + accVp[1][jtl][r] * accVp[1][jtl][r]
                     + accVp[2][jtl][r] * accVp[2][jtl][r];
            UV_lds[n * 132 + jcol] = uv;
            float vn = sqrtf(nn);
            ushort hh = f2b(vn);
            x_hi[n * 264 + jcol] = hh;
            x_lo[n * 264 + jcol] = f2b(vn - b2f(hh));
        }
    }
    for (int it = 0; it < 8; it++) {
        int t8 = it * 256 + tid;
        int n = t8 >> 7, j = t8 & 127;
        float sv = s[(size_t)(n0 + n) * D + j];
        ushort hh = f2b(sv);
        x_hi[n * 264 + 128 + j] = hh;
        x_lo[n * 264 + 128 + j] = f2b(sv - b2f(hh));
    }
    __syncthreads();

    {
        f32x4 acc1[2];
        acc1[0] = (f32x4){0.f, 0.f, 0.f, 0.f};
        acc1[1] = (f32x4){0.f, 0.f, 0.f, 0.f};
        #pragma unroll
        for (int t = 0; t < 8; t++) {
            bf16x8 aH = *(const bf16x8*)&x_hi[arow * 264 + t * 32 + kg * 8];
            bf16x8 aL = *(const bf16x8*)&x_lo[arow * 264 + t * 32 + kg * 8];
            #pragma unroll
            for (int jtl = 0; jtl < 2; jtl++) {
                int j = (wave * 2 + jtl) * 16 + arow;
                bf16x8 bH = *(const bf16x8*)&u1t[(size_t)j * 256 + t * 32 + kg * 8];
                bf16x8 bL = *(const bf16x8*)&u1t[(size_t)2 * D * D + (size_t)j * 256 + t * 32 + kg * 8];
                MFMA3(acc1[jtl], aH, aL, bH, bL)
            }
        }
        #pragma unroll
        for (int jtl = 0; jtl < 2; jtl++) {
            int j = (wave * 2 + jtl) * 16 + arow;
            float bias = ub1[j];
            #pragma unroll
            for (int r = 0; r < 4; r++) {
                int n = kg * 4 + r;
                float hv = silu_f(acc1[jtl][r] + bias);
                ushort hh = f2b(hv);
                h_hi[n * 136 + j] = hh;
                h_lo[n * 136 + j] = f2b(hv - b2f(hh));
            }
        }
    }
    __syncthreads();

    f32x4 acc2[6];
    #pragma unroll
    for (int q = 0; q < 6; q++) acc2[q] = (f32x4){0.f, 0.f, 0.f, 0.f};
    #pragma unroll
    for (int t = 0; t < 4; t++) {
        bf16x8 aH = *(const bf16x8*)&h_hi[arow * 136 + t * 32 + kg * 8];
        bf16x8 aL = *(const bf16x8*)&h_lo[arow * 136 + t * 32 + kg * 8];
        #pragma unroll
        for (int q = 0; q < 6; q++) {
            int j = (wave * 6 + q) * 16 + arow;
            bf16x8 bH = *(const bf16x8*)&u2t[(size_t)j * 128 + t * 32 + kg * 8];
            bf16x8 bL = *(const bf16x8*)&u2t[(size_t)D3 * D + (size_t)j * 128 + t * 32 + kg * 8];
            MFMA3(acc2[q], aH, aL, bH, bL)
        }
    }
    __syncthreads();

    #pragma unroll
    for (int q = 0; q < 6; q++) {
        int j = (wave * 6 + q) * 16 + arow;
        float bias = ub2[j];
        #pragma unroll
        for (int r = 0; r < 4; r++)
            a_out[(kg * 4 + r) * 392 + j] = acc2[q][r] + bias;
    }
    __syncthreads();

    float snew_reg[8];
    #pragma unroll
    for (int it = 0; it < 8; it++) {
        int t8 = it * 256 + tid;
        int n = t8 >> 7, j = t8 & 127;
        float a0 = a_out[n * 392 + j];
        float a1 = a_out[n * 392 + 128 + j];
        float a2 = a_out[n * 392 + 256 + j];
        size_t sidx = (size_t)(n0 + n) * D + j;
        float snew = s[sidx] + a2 + UV_lds[n * 132 + j] * a1;
        s[sidx] = snew;
        snew_reg[it] = snew;
        float vf[3];
        #pragma unroll
        for (int i = 0; i < 3; i++) {
            size_t idx = ((size_t)(n0 + n) * 3 + i) * D + j;
            vf[i] = v[idx] + b2f(U_lds[(i * 16 + n) * 136 + j]) * a0;
            v[idx] = vf[i];
        }
        if (FUSE) {
            ushort* pvp = pv + ((size_t)(n0 + n) * 128 + j) * 6;
            pvp[3] = f2b(vf[0]);
            pvp[4] = f2b(vf[1]);
            pvp[5] = f2b(vf[2]);
        }
    }

    if (!FUSE) return;

    __syncthreads();
    #pragma unroll
    for (int it = 0; it < 8; it++) {
        int t8 = it * 256 + tid;
        int n = t8 >> 7, j = t8 & 127;
        float sv = snew_reg[it];
        ushort hh = f2b(sv);
        x_hi[n * 264 + j] = hh;
        x_lo[n * 264 + j] = f2b(sv - b2f(hh));
    }
    __syncthreads();

    {
        f32x4 accp[2];
        accp[0] = (f32x4){0.f, 0.f, 0.f, 0.f};
        accp[1] = (f32x4){0.f, 0.f, 0.f, 0.f};
        #pragma unroll
        for (int t = 0; t < 4; t++) {
            bf16x8 aH = *(const bf16x8*)&x_hi[arow * 264 + t * 32 + kg * 8];
            bf16x8 aL = *(const bf16x8*)&x_lo[arow * 264 + t * 32 + kg * 8];
            #pragma unroll
            for (int jtl = 0; jtl < 2; jtl++) {
                int j = (wave * 2 + jtl) * 16 + arow;
                bf16x8 bH = *(const bf16x8*)&w1th[(size_t)j * 128 + t * 32 + kg * 8];
                bf16x8 bL = *(const bf16x8*)&w1tl[(size_t)j * 128 + t * 32 + kg * 8];
                MFMA3(accp[jtl], aH, aL, bH, bL)
            }
        }
        __syncthreads();
        #pragma unroll
        for (int jtl = 0; jtl < 2; jtl++) {
            int j = (wave * 2 + jtl) * 16 + arow;
            float bias = pb1[j];
            #pragma unroll
            for (int r = 0; r < 4; r++) {
                int n = kg * 4 + r;
                float hv = silu_f(accp[jtl][r] + bias);
                ushort hh = f2b(hv);
                h_hi[n * 136 + j] = hh;
                h_lo[n * 136 + j] = f2b(hv - b2f(hh));
            }
        }
    }
    __syncthreads();

    {
        f32x4 accq[6];
        #pragma unroll
        for (int q = 0; q < 6; q++) accq[q] = (f32x4){0.f, 0.f, 0.f, 0.f};
        #pragma unroll
        for (int t = 0; t < 4; t++) {
            bf16x8 aH = *(const bf16x8*)&h_hi[arow * 136 + t * 32 + kg * 8];
            bf16x8 aL = *(const bf16x8*)&h_lo[arow * 136 + t * 32 + kg * 8];
            #pragma unroll
            for (int q = 0; q < 6; q++) {
                int j = (wave * 6 + q) * 16 + arow;
                bf16x8 bH = *(const bf16x8*)&w2th[(size_t)j * 128 + t * 32 + kg * 8];
                bf16x8 bL = *(const bf16x8*)&w2tl[(size_t)j * 128 + t * 32 + kg * 8];
                MFMA3(accq[q], aH, aL, bH, bL)
            }
        }
        #pragma unroll
        for (int q = 0; q < 6; q++) {
            int j = (wave * 6 + q) * 16 + arow;
            float bias = pb2[j];
            int seg = j >> 7;
            int ch  = j & 127;
            #pragma unroll
            for (int r = 0; r < 4; r++) {
                pv[((size_t)(n0 + kg * 4 + r) * 128 + ch) * 6 + seg] = f2b(accq[q][r] + bias);
            }
        }
    }
}

// ---------------------------------------------------------------- graph segment sum
__global__ __launch_bounds__(128) void graph_sum(
    const float* __restrict__ s, const int* __restrict__ gi, float* __restrict__ g)
{
    int d = threadIdx.x;
    int n0 = blockIdx.x * 64;
    int n1 = n0 + 64; if (n1 > NN) n1 = NN;
    if (n0 >= NN) return;
    int cur = gi[n0];
    float acc = 0.0f;
    for (int n = n0; n < n1; n++) {
        int gn = gi[n];
        if (gn != cur) { atomicAdd(&g[cur * D + d], acc); acc = 0.0f; cur = gn; }
        acc += s[n * D + d];
    }
    atomicAdd(&g[cur * D + d], acc);
}

// ---------------------------------------------------------------- readout
__global__ __launch_bounds__(128) void out_mlp(
    const float* __restrict__ g,
    const float* __restrict__ w1, const float* __restrict__ b1,
    const float* __restrict__ w2, const float* __restrict__ b2,
    float* __restrict__ out)
{
    __shared__ float gl[D];
    __shared__ float red[2];
    int j = threadIdx.x;
    int gr = blockIdx.x;
    gl[j] = g[gr * D + j];
    __syncthreads();
    float acc = b1[j];
    for (int k = 0; k < D; k++) acc += gl[k] * w1[k * D + j];
    float h = silu_f(acc) * w2[j];
    #pragma unroll
    for (int off = 32; off >= 1; off >>= 1) h += __shfl_down(h, off);
    if ((j & 63) == 0) red[j >> 6] = h;
    __syncthreads();
    if (j == 0) out[gr] = red[0] + red[1] + b2[0];
}

// ================================================================ launch
extern "C" void kernel_launch(void* const* d_in, const int* in_sizes, int n_in,
                              void* d_out, int out_size, void* d_ws, size_t ws_size,
                              hipStream_t stream)
{
    const int*   edge_src   = (const int*)  d_in[0];
    const int*   edge_dst   = (const int*)  d_in[1];
    const float* edge_vec   = (const float*)d_in[2];
    const int*   atom_types = (const int*)  d_in[3];
    const int*   node_gi    = (const int*)  d_in[4];
    const float* embedding  = (const float*)d_in[5];
    const float* phi_w1     = (const float*)d_in[6];
    const float* phi_b1     = (const float*)d_in[7];
    const float* phi_w2     = (const float*)d_in[8];
    const float* phi_b2     = (const float*)d_in[9];
    const float* filt_w     = (const float*)d_in[10];
    const float* filt_b     = (const float*)d_in[11];
    const float* upd_w1     = (const float*)d_in[12];
    const float* upd_b1     = (const float*)d_in[13];
    const float* upd_w2     = (const float*)d_in[14];
    const float* upd_b2     = (const float*)d_in[15];
    const float* U_w        = (const float*)d_in[16];
    const float* V_w        = (const float*)d_in[17];
    const float* out_w1     = (const float*)d_in[18];
    const float* out_b1     = (const float*)d_in[19];
    const float* out_w2     = (const float*)d_in[20];
    const float* out_b2     = (const float*)d_in[21];

    float* ws = (float*)d_ws;
    size_t o = 0;
    float* s_a   = ws + o; o += (size_t)NN * D;
    float* s_b   = ws + o; o += (size_t)NN * D;
    float* v_a   = ws + o; o += (size_t)NN * 3 * D;
    float* v_b   = ws + o; o += (size_t)NN * 3 * D;
    float* pv_f  = ws + o; o += (size_t)NN * 384;             // pv: [n][128][6] bf16
    float* rbf_f = ws + o; o += (size_t)NE * RBF_ROW;         // fp32, padded rows
    float* geo   = ws + o; o += (size_t)NE * 4;
    float* g     = ws + o; o += (size_t)NG * D;
    float* w1t_f = ws + o; o += (size_t)D * D;                // phi w1 hi+lo
    float* w2t_f = ws + o; o += (size_t)D3 * D;               // phi w2 hi+lo
    float* uwt_f = ws + o; o += (size_t)D * D;                // Uw^T hi+lo
    float* vwt_f = ws + o; o += (size_t)D * D;                // Vw^T hi+lo
    float* u1t_f = ws + o; o += (size_t)2 * D * D;            // upd_w1^T hi+lo
    float* u2t_f = ws + o; o += (size_t)D3 * D;               // upd_w2^T hi+lo
    float* ptab_f= ws + o; o += (size_t)10 * D;               // round-0 phi table
    int* deg     = (int*)(ws + o); o += NN;
    int* offs    = (int*)(ws + o); o += NN + 1;
    int* cursor  = (int*)(ws + o); o += NN;
    int* perm    = (int*)(ws + o); o += NN;
    int* bpos    = (int*)(ws + o); o += 64;
    int* eidb    = (int*)(ws + o); o += NE;

    ushort* pv    = (ushort*)pv_f;
    ushort* w1th  = (ushort*)w1t_f;
    ushort* w1tl  = w1th + (size_t)D * D;
    ushort* w2th  = (ushort*)w2t_f;
    ushort* w2tl  = w2th + (size_t)D3 * D;
    ushort* uwt   = (ushort*)uwt_f;
    ushort* vwt   = (ushort*)vwt_f;
    ushort* u1t   = (ushort*)u1t_f;
    ushort* u2t   = (ushort*)u2t_f;
    uint*   ptab  = (uint*)ptab_f;

    mega_init<<<512, 256, 0, stream>>>(g, deg, phi_w1, phi_w2,
                                       w1th, w1tl, w2th, w2tl,
                                       U_w, V_w, upd_w1, upd_w2,
                                       uwt, vwt, u1t, u2t);
    csr_count<<<(NE + 255) / 256, 256, 0, stream>>>(edge_dst, deg);
    scan_all<<<1, 1024, 0, stream>>>(deg, offs, cursor, bpos);
    scatter_all<<<(NE + 255) / 256, 256, 0, stream>>>(edge_dst, cursor, eidb,
                                                      deg, bpos, perm);
    edge_geom<<<(NE + 255) / 256, 256, 0, stream>>>(edge_vec, rbf_f, (float4*)geo);
    phi10<<<10, 128, 0, stream>>>(embedding, phi_w1, phi_b1, phi_w2, phi_b2, ptab);

    // round 0 (v = 0 specialization)
    node_gather_r0<<<NN / 4, 512, 0, stream>>>(eidb, offs, perm, edge_src,
                                               atom_types, embedding, ptab,
                                               rbf_f, (const float4*)geo,
                                               filt_w, filt_b, s_b, v_b);
    node_vupd_mfma<true><<<NN / 16, 256, 0, stream>>>(s_b, v_b, pv,
                                                      uwt, vwt, u1t, u2t,
                                                      upd_b1, upd_b2,
                                                      w1th, w1tl, phi_b1,
                                                      w2th, w2tl, phi_b2);
    // round 1
    node_gather<<<NN / 4, 512, 0, stream>>>(eidb, offs, perm, edge_src, pv,
                                            s_b, v_b, rbf_f,
                                            (const float4*)geo, filt_w, filt_b,
                                            s_a, v_a);
    node_vupd_mfma<false><<<NN / 16, 256, 0, stream>>>(s_a, v_a, pv,
                                                       uwt, vwt, u1t, u2t,
                                                       upd_b1, upd_b2,
                                                       w1th, w1tl, phi_b1,
                                                       w2th, w2tl, phi_b2);

    graph_sum<<<(NN + 63) / 64, 128, 0, stream>>>(s_a, node_gi, g);
    out_mlp<<<NG, 128, 0, stream>>>(g, out_w1, out_b1, out_w2, out_b2, (float*)d_out);
}